// Round 3
// baseline (4269.518 us; speedup 1.0000x reference)
//
#include <hip/hip_runtime.h>
#include <math.h>

// ---------------- problem geometry ----------------
constexpr int S1 = 66, S1_2 = S1*S1, S1_3 = S1*S1*S1;   // 4356, 287496
constexpr int S2 = 33, S2_2 = S2*S2, S2_3 = S2*S2*S2;   // 1089, 35937
constexpr int S3 = 64, S3_2 = S3*S3, S3_3 = S3*S3*S3;   // 4096, 262144
constexpr int NG = 8;    // groups
constexpr int CG = 8;    // channels per group
constexpr int D  = 64;   // total channels

// ---------------- d_out layout (floats) ----------------
constexpr size_t X_OFF     = 0;                                   // x: 64*64^3 = 16,777,216
constexpr size_t HELM_OFF  = (size_t)D*S3_3;                      // helm: 8*4*66^3 = 9,199,872
constexpr size_t VEL_OFF   = HELM_OFF + (size_t)NG*4*S1_3;        // 25,977,088
constexpr size_t VPHI_OFF  = VEL_OFF  + (size_t)NG*3*S3_3;        // 32,268,544
constexpr size_t VVORT_OFF = VPHI_OFF + (size_t)NG*3*S3_3;        // 38,560,000

// ---------------- d_ws layout (floats) ----------------
// peak-need ~80.5 MB; large intermediates live in not-yet-final d_out regions.
constexpr size_t CORR_OFF  = 0;                                   // 8*54*33^3 = 15,524,784
constexpr size_t C1P_OFF   = CORR_OFF + (size_t)NG*54*S2_3;       // conv1 phi: 8*8*33^3
constexpr size_t C1V_OFF   = C1P_OFF  + (size_t)NG*8*S2_3;        // conv1 vort
constexpr size_t STATS_OFF = C1V_OFF  + (size_t)NG*8*S2_3;        // 64 floats (4 stat sets of 16)
// ws+0 is reused (after corr/conv1 are dead) for: conv2_phi, conv2_vort, phi1, pred
// (each <= CORR+C1P+C1V = 20,124,720 floats; conv2 needs 18,399,744; pred 16,777,216)

// =====================================================================
// encoder: (prev|next)*m  -> conv 2x2x2 stride2 +bias : (8g,8ic,66^3)->(8g,64oc,33^3)
// =====================================================================
__global__ void __launch_bounds__(256)
enc_kernel(const float* __restrict__ in, const float* __restrict__ msk,
           const float* __restrict__ w,  const float* __restrict__ b,
           float* __restrict__ out) {
    int pos = blockIdx.x*256 + threadIdx.x;
    int g = blockIdx.y;
    if (pos >= S2_3) return;
    int x = pos / S2_2, rem = pos % S2_2, y = rem / S2, z = rem % S2;
    int ib = 2*x*S1_2 + 2*y*S1 + 2*z;
    float mv[8];
#pragma unroll
    for (int c = 0; c < 8; ++c) {
        int dx = c>>2, dy = (c>>1)&1, dz = c&1;
        mv[c] = msk[ib + dx*S1_2 + dy*S1 + dz];
    }
    float mi[64];
#pragma unroll
    for (int ic = 0; ic < 8; ++ic) {
        const float* inc = in + (size_t)(g*CG + ic)*S1_3 + ib;
#pragma unroll
        for (int c = 0; c < 8; ++c) {
            int dx = c>>2, dy = (c>>1)&1, dz = c&1;
            mi[ic*8 + c] = inc[dx*S1_2 + dy*S1 + dz] * mv[c];
        }
    }
    for (int oc = 0; oc < 64; ++oc) {           // w index uniform -> s_load
        float acc = b[oc];
#pragma unroll
        for (int t = 0; t < 64; ++t) acc = fmaf(mi[t], w[oc*64 + t], acc);
        out[(size_t)(g*64 + oc)*S2_3 + pos] = acc;
    }
}

// =====================================================================
// correlation half: 9 dot-products over 64ch, replicated x3 with z-edge masks
// =====================================================================
__global__ void __launch_bounds__(256)
corr_kernel(const float* __restrict__ fpv, const float* __restrict__ fnv,
            float* __restrict__ corr, int base_ch) {
    int pos = blockIdx.x*256 + threadIdx.x;
    int g = blockIdx.y;
    if (pos >= S2_3) return;
    int x = pos / S2_2, rem = pos % S2_2, y = rem / S2, z = rem % S2;
    const float* fp = fpv + (size_t)g*64*S2_3;
    const float* fn = fnv + (size_t)g*64*S2_3;
    int   nidx[9];
    float nmask[9];
#pragma unroll
    for (int di = -1; di <= 1; ++di) {
        int xx = x + di; int xc = min(max(xx,0),S2-1); bool okx = (unsigned)xx < (unsigned)S2;
#pragma unroll
        for (int dj = -1; dj <= 1; ++dj) {
            int yy = y + dj; int yc = min(max(yy,0),S2-1);
            bool ok = okx && ((unsigned)yy < (unsigned)S2);
            nidx [(di+1)*3 + dj+1] = xc*S2_2 + yc*S2 + z;
            nmask[(di+1)*3 + dj+1] = ok ? 1.f : 0.f;
        }
    }
    float acc[9] = {0,0,0,0,0,0,0,0,0};
    for (int c = 0; c < 64; ++c) {
        float pc = fp[(size_t)c*S2_3 + pos];
        const float* fnc = fn + (size_t)c*S2_3;
#pragma unroll
        for (int s = 0; s < 9; ++s) acc[s] = fmaf(pc, fnc[nidx[s]]*nmask[s], acc[s]);
    }
    const float inv64 = 1.f/64.f;
#pragma unroll
    for (int k = 0; k < 3; ++k) {
        float zf = ((k==0 && z==S2-1) || (k==2 && z==0)) ? 0.f : inv64;
#pragma unroll
        for (int s = 0; s < 9; ++s)
            corr[(size_t)(g*54 + base_ch + k*9 + s)*S2_3 + pos] = acc[s]*zf;
    }
}

// =====================================================================
// generic 3x3x3 pad-1 conv, NIC -> 8, at S^3 (no bias; BN follows)
// =====================================================================
template<int NIC, int S_>
__global__ void __launch_bounds__(256)
conv3_kernel(const float* __restrict__ in, const float* __restrict__ w,
             float* __restrict__ out) {
    constexpr int SS = S_*S_, SSS = S_*S_*S_;
    int pos = blockIdx.x*256 + threadIdx.x;
    int g = blockIdx.y;
    if (pos >= SSS) return;
    int x = pos / SS, rem = pos % SS, y = rem / S_, z = rem % S_;
    float acc[8] = {0,0,0,0,0,0,0,0};
    for (int ic = 0; ic < NIC; ++ic) {
        const float* inc = in + (size_t)(g*NIC + ic)*SSS;
        float v[27];
#pragma unroll
        for (int dx = -1; dx <= 1; ++dx) {
            int xx = x + dx; int xc = min(max(xx,0),S_-1); bool okx = (unsigned)xx < (unsigned)S_;
#pragma unroll
            for (int dy = -1; dy <= 1; ++dy) {
                int yy = y + dy; int yc = min(max(yy,0),S_-1);
                bool oky = okx && ((unsigned)yy < (unsigned)S_);
#pragma unroll
                for (int dz = -1; dz <= 1; ++dz) {
                    int zz = z + dz; int zc = min(max(zz,0),S_-1);
                    bool ok = oky && ((unsigned)zz < (unsigned)S_);
                    float t = inc[xc*SS + yc*S_ + zc];
                    v[(dx+1)*9 + (dy+1)*3 + (dz+1)] = ok ? t : 0.f;
                }
            }
        }
#pragma unroll
        for (int oc = 0; oc < 8; ++oc) {
            const float* wr = w + (size_t)(oc*NIC + ic)*27;   // uniform -> s_load
#pragma unroll
            for (int t = 0; t < 27; ++t) acc[oc] = fmaf(v[t], wr[t], acc[oc]);
        }
    }
#pragma unroll
    for (int oc = 0; oc < 8; ++oc)
        out[(size_t)(g*8 + oc)*SSS + pos] = acc[oc];
}

// =====================================================================
// BN stats: one block per channel, f64 accumulate over 8 groups x npos
// stats[ch*2] = mean, stats[ch*2+1] = 1/sqrt(var+eps)
// =====================================================================
__global__ void __launch_bounds__(1024)
bn_stats_kernel(const float* __restrict__ in, int npos, float* __restrict__ stats) {
    int ch = blockIdx.x;
    int tid = threadIdx.x;
    double s = 0.0, ss = 0.0;
    for (int g = 0; g < NG; ++g) {
        const float* p = in + (size_t)(g*8 + ch)*npos;
        for (int i = tid; i < npos; i += 1024) { double v = p[i]; s += v; ss += v*v; }
    }
    __shared__ double sd[1024], sd2[1024];
    sd[tid] = s; sd2[tid] = ss; __syncthreads();
    for (int o = 512; o > 0; o >>= 1) {
        if (tid < o) { sd[tid] += sd[tid+o]; sd2[tid] += sd2[tid+o]; }
        __syncthreads();
    }
    if (tid == 0) {
        double n = (double)npos * NG;
        double mean = sd[0]/n;
        double var  = sd2[0]/n - mean*mean;
        stats[ch*2]   = (float)mean;
        stats[ch*2+1] = (float)(1.0/sqrt(var + 1e-5));
    }
}

// =====================================================================
// fused BN + ReLU + x2 trilinear (align-corners-style) upsample 33^3 -> 66^3
// =====================================================================
__global__ void __launch_bounds__(256)
bn_relu_up_kernel(const float* __restrict__ in, const float* __restrict__ stats,
                  const float* __restrict__ gamma, const float* __restrict__ beta,
                  float* __restrict__ out) {
    int pos = blockIdx.x*256 + threadIdx.x;
    if (pos >= S1_3) return;
    int gc = blockIdx.y;           // g*8+ch
    int ch = gc & 7;
    int X = pos / S1_2, rem = pos % S1_2, Y = rem / S1, Z = rem % S1;
    const float scale = (float)(32.0/65.0);
    float sx = (float)X*scale, sy = (float)Y*scale, sz = (float)Z*scale;
    int x0 = (int)floorf(sx), y0 = (int)floorf(sy), z0 = (int)floorf(sz);
    float wx = sx - (float)x0, wy = sy - (float)y0, wz = sz - (float)z0;
    int x1 = min(x0+1, S2-1), y1 = min(y0+1, S2-1), z1 = min(z0+1, S2-1);
    float a = stats[ch*2+1]*gamma[ch];
    float c = beta[ch] - stats[ch*2]*a;
    const float* p = in + (size_t)gc*S2_3;
    auto val = [&](int xi, int yi, int zi) {
        float t = fmaf(p[xi*S2_2 + yi*S2 + zi], a, c);
        return t > 0.f ? t : 0.f;
    };
    float t00 = val(x0,y0,z0)*(1.f-wx) + val(x1,y0,z0)*wx;
    float t10 = val(x0,y1,z0)*(1.f-wx) + val(x1,y1,z0)*wx;
    float t01 = val(x0,y0,z1)*(1.f-wx) + val(x1,y0,z1)*wx;
    float t11 = val(x0,y1,z1)*(1.f-wx) + val(x1,y1,z1)*wx;
    float u0 = t00*(1.f-wy) + t10*wy;
    float u1 = t01*(1.f-wy) + t11*wy;
    out[(size_t)gc*S1_3 + pos] = u0*(1.f-wz) + u1*wz;
}

// =====================================================================
// fused BN + ReLU + 1x1x1 conv (+bias, *scale) -> helm channels
// =====================================================================
template<int NOC>
__global__ void __launch_bounds__(256)
outconv_kernel(const float* __restrict__ in, const float* __restrict__ stats,
               const float* __restrict__ gamma, const float* __restrict__ beta,
               const float* __restrict__ ow, const float* __restrict__ ob,
               const float* __restrict__ wscale, float extra,
               float* __restrict__ helm, int oc_off) {
    int pos = blockIdx.x*256 + threadIdx.x;
    int g = blockIdx.y;
    if (pos >= S1_3) return;
    float r[8];
#pragma unroll
    for (int ic = 0; ic < 8; ++ic) {
        float a = stats[ic*2+1]*gamma[ic];
        float c = beta[ic] - stats[ic*2]*a;
        float t = fmaf(in[(size_t)(g*8 + ic)*S1_3 + pos], a, c);
        r[ic] = t > 0.f ? t : 0.f;
    }
    float sc = wscale[0]*extra;
#pragma unroll
    for (int oc = 0; oc < NOC; ++oc) {
        float acc = ob[oc];
#pragma unroll
        for (int ic = 0; ic < 8; ++ic) acc = fmaf(r[ic], ow[oc*8 + ic], acc);
        helm[(size_t)(g*4 + oc_off + oc)*S1_3 + pos] = acc*sc;
    }
}

// =====================================================================
// velocity: helm (8,4,66^3) -> vel_phi, vel_vort, vel (8,3,64^3)
// stencils collapsed to closed-form (all indices in-bounds by construction)
// =====================================================================
__global__ void __launch_bounds__(256)
velocity_kernel(const float* __restrict__ helm, float* __restrict__ vel,
                float* __restrict__ vphi, float* __restrict__ vvort) {
    int pos = blockIdx.x*256 + threadIdx.x;
    int g = blockIdx.y;
    if (pos >= S3_3) return;
    int x = pos / S3_2, rem = pos % S3_2, y = rem / S3, z = rem % S3;
    const float* H = helm + (size_t)g*4*S1_3;
    auto idx = [&](int c, int i, int j, int k) { return (size_t)c*S1_3 + i*S1_2 + j*S1 + k; };
    // phi (channel 0)
    float pu = 0.5f*(H[idx(0,x+1,y+1,z+2)] - H[idx(0,x+1,y+1,z  )]);
    float pv = 0.5f*(H[idx(0,x+1,y+2,z+1)] - H[idx(0,x+1,y  ,z+1)]);
    float pw = 0.5f*(H[idx(0,x+2,y+1,z+1)] - H[idx(0,x  ,y+1,z+1)]);
    // stream: s0=ch1, s1=ch2, s2=ch3
    float vu = 0.5f*( (H[idx(2,x+2,y+1,z+1)]-H[idx(2,x+1,y+1,z+1)]) - (H[idx(1,x+1,y+2,z+1)]-H[idx(1,x+1,y+1,z+1)])
                    + (H[idx(2,x+2,y+1,z  )]-H[idx(2,x+1,y+1,z  )]) - (H[idx(1,x+1,y+2,z  )]-H[idx(1,x+1,y+1,z  )]) );
    float vv = 0.5f*( (H[idx(1,x+1,y+1,z+2)]-H[idx(1,x+1,y+1,z+1)]) - (H[idx(3,x+2,y+1,z+1)]-H[idx(3,x+1,y+1,z+1)])
                    + (H[idx(1,x+1,y  ,z+2)]-H[idx(1,x+1,y  ,z+1)]) - (H[idx(3,x+2,y  ,z+1)]-H[idx(3,x+1,y  ,z+1)]) );
    float vw = 0.5f*( (H[idx(3,x+1,y+2,z+1)]-H[idx(3,x+1,y+1,z+1)]) - (H[idx(2,x+1,y+1,z+2)]-H[idx(2,x+1,y+1,z+1)])
                    + (H[idx(3,x  ,y+2,z+1)]-H[idx(3,x  ,y+1,z+1)]) - (H[idx(2,x  ,y+1,z+2)]-H[idx(2,x  ,y+1,z+1)]) );
    size_t o0 = (size_t)(g*3+0)*S3_3 + pos;
    size_t o1 = (size_t)(g*3+1)*S3_3 + pos;
    size_t o2 = (size_t)(g*3+2)*S3_3 + pos;
    vphi[o0] = pu;      vphi[o1] = pv;      vphi[o2] = pw;
    vvort[o0] = vu;     vvort[o1] = vv;     vvort[o2] = vw;
    vel[o0] = pu + vu;  vel[o1] = pv + vv;  vel[o2] = pw + vw;
}

// =====================================================================
// trilinear advection. BFECC variant samples (tex + 0.5*(tex - phi2)).
// =====================================================================
template<bool BFECC>
__global__ void __launch_bounds__(256)
advect_kernel(const float* __restrict__ f, const float* __restrict__ f2,
              const float* __restrict__ vel, float vsign,
              float* __restrict__ out) {
    int pos = blockIdx.x*256 + threadIdx.x;
    int g = blockIdx.y;
    if (pos >= S3_3) return;
    int x = pos / S3_2, rem = pos % S3_2, y = rem / S3, z = rem % S3;
    float px = (float)x - vsign*vel[(size_t)(g*3+2)*S3_3 + pos];
    float py = (float)y - vsign*vel[(size_t)(g*3+1)*S3_3 + pos];
    float pz = (float)z - vsign*vel[(size_t)(g*3+0)*S3_3 + pos];
    px = fminf(fmaxf(px, 0.f), 63.f);
    py = fminf(fmaxf(py, 0.f), 63.f);
    pz = fminf(fmaxf(pz, 0.f), 63.f);
    int x0 = (int)floorf(px), y0 = (int)floorf(py), z0 = (int)floorf(pz);
    int x1 = min(x0+1, S3-1), y1 = min(y0+1, S3-1), z1 = min(z0+1, S3-1);
    float fx = px - (float)x0, fy = py - (float)y0, fz = pz - (float)z0;
    int xo0 = x0*S3_2, xo1 = x1*S3_2, yo0 = y0*S3, yo1 = y1*S3;
    int i000 = xo0+yo0+z0, i100 = xo1+yo0+z0, i010 = xo0+yo1+z0, i110 = xo1+yo1+z0;
    int i001 = xo0+yo0+z1, i101 = xo1+yo0+z1, i011 = xo0+yo1+z1, i111 = xo1+yo1+z1;
    for (int c = 0; c < 8; ++c) {
        const float* fc  = f  + (size_t)(g*8 + c)*S3_3;
        const float* f2c = BFECC ? (f2 + (size_t)(g*8 + c)*S3_3) : nullptr;
        auto corner = [&](int i) {
            float t = fc[i];
            if (BFECC) { float p = f2c[i]; t = t + 0.5f*(t - p); }
            return t;
        };
        float g000 = corner(i000), g100 = corner(i100), g010 = corner(i010), g110 = corner(i110);
        float g001 = corner(i001), g101 = corner(i101), g011 = corner(i011), g111 = corner(i111);
        float r = ((g000*(1.f-fx) + g100*fx)*(1.f-fy) + (g010*(1.f-fx) + g110*fx)*fy)*(1.f-fz)
                + ((g001*(1.f-fx) + g101*fx)*(1.f-fy) + (g011*(1.f-fx) + g111*fx)*fy)*fz;
        out[(size_t)(g*8 + c)*S3_3 + pos] = r;
    }
}

// =====================================================================
// LayerNorm(64ch) + Linear(64,64) + GELU(exact) + Linear(64,64) + residual
// one thread per spatial position; weights via uniform s_loads
// =====================================================================
__global__ void __launch_bounds__(256)
ln_mlp_kernel(const float* __restrict__ pred,
              const float* __restrict__ lng, const float* __restrict__ lnb,
              const float* __restrict__ w1, const float* __restrict__ b1,
              const float* __restrict__ w2, const float* __restrict__ b2,
              float* __restrict__ xout) {
    int pos = blockIdx.x*256 + threadIdx.x;
    if (pos >= S3_3) return;
    // pass 1: mean / var
    float s = 0.f, ss = 0.f;
    for (int i = 0; i < 64; ++i) {
        float v = pred[(size_t)i*S3_3 + pos];
        s += v; ss += v*v;
    }
    float mu = s*(1.f/64.f);
    float var = ss*(1.f/64.f) - mu*mu;
    float rs = rsqrtf(var + 1e-5f);
    // pass 2: y1 = LN(h) @ w1 + b1
    float y1[64];
#pragma unroll
    for (int j = 0; j < 64; ++j) y1[j] = b1[j];
    for (int i = 0; i < 64; ++i) {
        float v = pred[(size_t)i*S3_3 + pos];
        float hn = (v - mu)*rs*lng[i] + lnb[i];
        const float* wr = w1 + i*64;          // uniform -> s_load_dwordx
#pragma unroll
        for (int j = 0; j < 64; ++j) y1[j] = fmaf(hn, wr[j], y1[j]);
    }
#pragma unroll
    for (int j = 0; j < 64; ++j) {
        float t = y1[j];
        y1[j] = 0.5f*t*(1.f + erff(t*0.70710678118654752f));
    }
    // pass 3: out = pred + y1 @ w2 + b2
    for (int c = 0; c < 64; ++c) {
        float acc = b2[c];
#pragma unroll
        for (int j = 0; j < 64; ++j) acc = fmaf(y1[j], w2[j*64 + c], acc);
        xout[(size_t)c*S3_3 + pos] = pred[(size_t)c*S3_3 + pos] + acc;
    }
}

// =====================================================================
extern "C" void kernel_launch(void* const* d_in, const int* in_sizes, int n_in,
                              void* d_out, int out_size, void* d_ws, size_t ws_size,
                              hipStream_t stream) {
    const float* prev       = (const float*)d_in[0];
    const float* nxt        = (const float*)d_in[1];
    const float* tex        = (const float*)d_in[2];
    const float* mask       = (const float*)d_in[3];
    const float* boundary   = (const float*)d_in[4];
    const float* enc_w      = (const float*)d_in[5];
    const float* enc_b      = (const float*)d_in[6];
    const float* phi_c1_w   = (const float*)d_in[7];
    const float* phi_bn1_g  = (const float*)d_in[8];
    const float* phi_bn1_b  = (const float*)d_in[9];
    const float* phi_c2_w   = (const float*)d_in[10];
    const float* phi_bn2_g  = (const float*)d_in[11];
    const float* phi_bn2_b  = (const float*)d_in[12];
    const float* phi_out_w  = (const float*)d_in[13];
    const float* phi_out_b  = (const float*)d_in[14];
    const float* vort_c1_w  = (const float*)d_in[15];
    const float* vort_bn1_g = (const float*)d_in[16];
    const float* vort_bn1_b = (const float*)d_in[17];
    const float* vort_c2_w  = (const float*)d_in[18];
    const float* vort_bn2_g = (const float*)d_in[19];
    const float* vort_bn2_b = (const float*)d_in[20];
    const float* vort_out_w = (const float*)d_in[21];
    const float* vort_out_b = (const float*)d_in[22];
    const float* phi_weight = (const float*)d_in[23];
    const float* vort_weight= (const float*)d_in[24];
    const float* ln_g       = (const float*)d_in[25];
    const float* ln_b       = (const float*)d_in[26];
    const float* ff_w1      = (const float*)d_in[27];
    const float* ff_b1      = (const float*)d_in[28];
    const float* ff_w2      = (const float*)d_in[29];
    const float* ff_b2      = (const float*)d_in[30];

    float* ws  = (float*)d_ws;
    float* out = (float*)d_out;

    float* w_corr  = ws + CORR_OFF;
    float* w_c1p   = ws + C1P_OFF;
    float* w_c1v   = ws + C1V_OFF;
    float* w_stats = ws + STATS_OFF;
    float* w_big   = ws;                 // reused: conv2_phi / conv2_vort / phi1 / pred

    // d_out regions used as early scratch (fully rewritten before return):
    float* o_x    = out + X_OFF;         // f_nm / up_phi / phi2 (tail into helm for up_phi)
    float* o_helm = out + HELM_OFF;
    float* o_vel  = out + VEL_OFF;       // f_pm,f_pb / up_vort (vel written later)
    float* o_vphi = out + VPHI_OFF;
    float* o_vvort= out + VVORT_OFF;

    dim3 b256(256), b1024(1024);
    dim3 gs2((S2_3 + 255)/256, NG);      // 141 x 8
    dim3 gs1((S1_3 + 255)/256, NG);      // 1124 x 8
    dim3 gs1c((S1_3 + 255)/256, NG*CG);  // 1124 x 64
    dim3 gs3((S3_3 + 255)/256, NG);      // 1024 x 8
    dim3 gmlp((S3_3 + 255)/256);         // 1024

    // ---- encoder + correlation ----
    enc_kernel<<<gs2, b256, 0, stream>>>(nxt,  mask,     enc_w, enc_b, o_x);   // f_nm
    enc_kernel<<<gs2, b256, 0, stream>>>(prev, mask,     enc_w, enc_b, o_vel); // f_pm
    corr_kernel<<<gs2, b256, 0, stream>>>(o_vel, o_x, w_corr, 0);
    enc_kernel<<<gs2, b256, 0, stream>>>(prev, boundary, enc_w, enc_b, o_vel); // f_pb
    corr_kernel<<<gs2, b256, 0, stream>>>(o_vel, o_x, w_corr, 27);

    // ---- conv1 (54->8, 33^3) + BN stats ----
    conv3_kernel<54,33><<<gs2, b256, 0, stream>>>(w_corr, phi_c1_w,  w_c1p);
    conv3_kernel<54,33><<<gs2, b256, 0, stream>>>(w_corr, vort_c1_w, w_c1v);
    bn_stats_kernel<<<8, b1024, 0, stream>>>(w_c1p, S2_3, w_stats + 0);
    bn_stats_kernel<<<8, b1024, 0, stream>>>(w_c1v, S2_3, w_stats + 16);

    // ---- BN+ReLU+upsample to 66^3 (into dead d_out scratch) ----
    bn_relu_up_kernel<<<gs1c, b256, 0, stream>>>(w_c1p, w_stats + 0,  phi_bn1_g,  phi_bn1_b,  o_x);
    bn_relu_up_kernel<<<gs1c, b256, 0, stream>>>(w_c1v, w_stats + 16, vort_bn1_g, vort_bn1_b, o_vel);

    // ---- conv2 + BN stats + out-conv, phi then vort (sharing ws+0) ----
    conv3_kernel<8,66><<<gs1, b256, 0, stream>>>(o_x, phi_c2_w, w_big);
    bn_stats_kernel<<<8, b1024, 0, stream>>>(w_big, S1_3, w_stats + 32);
    outconv_kernel<1><<<gs1, b256, 0, stream>>>(w_big, w_stats + 32, phi_bn2_g, phi_bn2_b,
                                                phi_out_w, phi_out_b, phi_weight, 1.0f,
                                                o_helm, 0);
    conv3_kernel<8,66><<<gs1, b256, 0, stream>>>(o_vel, vort_c2_w, w_big);
    bn_stats_kernel<<<8, b1024, 0, stream>>>(w_big, S1_3, w_stats + 48);
    outconv_kernel<3><<<gs1, b256, 0, stream>>>(w_big, w_stats + 48, vort_bn2_g, vort_bn2_b,
                                                vort_out_w, vort_out_b, vort_weight, 66.0f,
                                                o_helm, 1);

    // ---- velocities (writes final vel / vel_phi / vel_vort) ----
    velocity_kernel<<<gs3, b256, 0, stream>>>(o_helm, o_vel, o_vphi, o_vvort);

    // ---- BFECC advection ----
    advect_kernel<false><<<gs3, b256, 0, stream>>>(tex,   nullptr, o_vel,  1.f, w_big); // phi1 -> ws
    advect_kernel<false><<<gs3, b256, 0, stream>>>(w_big, nullptr, o_vel, -1.f, o_x);   // phi2 -> x region
    advect_kernel<true ><<<gs3, b256, 0, stream>>>(tex,   o_x,     o_vel,  1.f, w_big); // pred -> ws

    // ---- LayerNorm + MLP + residual (writes final x) ----
    ln_mlp_kernel<<<gmlp, b256, 0, stream>>>(w_big, ln_g, ln_b, ff_w1, ff_b1, ff_w2, ff_b2, o_x);
}

// Round 8
// 2883.760 us; speedup vs baseline: 1.4805x; 1.4805x over previous
//
#include <hip/hip_runtime.h>
#include <math.h>

// ---------------- problem geometry ----------------
constexpr int S1 = 66, S1_2 = S1*S1, S1_3 = S1*S1*S1;   // 4356, 287496
constexpr int S2 = 33, S2_2 = S2*S2, S2_3 = S2*S2*S2;   // 1089, 35937
constexpr int S3 = 64, S3_2 = S3*S3, S3_3 = S3*S3*S3;   // 4096, 262144
constexpr int NG = 8;    // groups
constexpr int CG = 8;    // channels per group
constexpr int D  = 64;   // total channels

// ---------------- d_out layout (floats) ----------------
constexpr size_t X_OFF     = 0;                                   // x: 64*64^3 = 16,777,216
constexpr size_t HELM_OFF  = (size_t)D*S3_3;                      // helm: 8*4*66^3 = 9,199,872
constexpr size_t VEL_OFF   = HELM_OFF + (size_t)NG*4*S1_3;        // 25,977,088
constexpr size_t VPHI_OFF  = VEL_OFF  + (size_t)NG*3*S3_3;        // 32,268,544
constexpr size_t VVORT_OFF = VPHI_OFF + (size_t)NG*3*S3_3;        // 38,560,000

// ---------------- d_ws layout (floats) ----------------
constexpr size_t CORR_OFF  = 0;                                   // 8*54*33^3 = 15,524,784
constexpr size_t C1P_OFF   = CORR_OFF + (size_t)NG*54*S2_3;       // conv1 phi: 8*8*33^3
constexpr size_t C1V_OFF   = C1P_OFF  + (size_t)NG*8*S2_3;        // conv1 vort
constexpr size_t STATS_OFF = C1V_OFF  + (size_t)NG*8*S2_3;        // 64 floats (4 stat sets of 16)
// ws+0 is reused (after corr/conv1 are dead) for: conv2_phi, conv2_vort, phi1, pred

// BN partial sums (8 ch x 256 blk x 2 doubles = 32 KB) live at the START OF
// THE X REGION of d_out. Liveness at all four stat points:
//  - conv1 stats: f_nm (X) already consumed by both corr launches -> dead;
//    up_phi overwrites X only AFTER bn_finish (stream-ordered).
//  - conv2-phi stats: up_phi (X) already consumed by the preceding conv3.
//  - conv2-vort stats: X dead (phi2/x written later).
// NOTE: do NOT use vel_phi region — up_vort spans VEL+VPHI+VVORT and is live
// until the vort conv2 (round-4 bug).
constexpr int NBLK_STAT = 256;

// =====================================================================
// encoder: (prev|next)*m  -> conv 2x2x2 stride2 +bias : (8g,8ic,66^3)->(8g,64oc,33^3)
// =====================================================================
__global__ void __launch_bounds__(256)
enc_kernel(const float* __restrict__ in, const float* __restrict__ msk,
           const float* __restrict__ w,  const float* __restrict__ b,
           float* __restrict__ out) {
    int pos = blockIdx.x*256 + threadIdx.x;
    int g = blockIdx.y;
    if (pos >= S2_3) return;
    int x = pos / S2_2, rem = pos % S2_2, y = rem / S2, z = rem % S2;
    int ib = 2*x*S1_2 + 2*y*S1 + 2*z;
    float mv[8];
#pragma unroll
    for (int c = 0; c < 8; ++c) {
        int dx = c>>2, dy = (c>>1)&1, dz = c&1;
        mv[c] = msk[ib + dx*S1_2 + dy*S1 + dz];
    }
    float mi[64];
#pragma unroll
    for (int ic = 0; ic < 8; ++ic) {
        const float* inc = in + (size_t)(g*CG + ic)*S1_3 + ib;
#pragma unroll
        for (int c = 0; c < 8; ++c) {
            int dx = c>>2, dy = (c>>1)&1, dz = c&1;
            mi[ic*8 + c] = inc[dx*S1_2 + dy*S1 + dz] * mv[c];
        }
    }
    for (int oc = 0; oc < 64; ++oc) {           // w index uniform -> s_load
        float acc = b[oc];
#pragma unroll
        for (int t = 0; t < 64; ++t) acc = fmaf(mi[t], w[oc*64 + t], acc);
        out[(size_t)(g*64 + oc)*S2_3 + pos] = acc;
    }
}

// =====================================================================
// correlation half: 9 dot-products over 64ch, replicated x3 with z-edge masks
// =====================================================================
__global__ void __launch_bounds__(256)
corr_kernel(const float* __restrict__ fpv, const float* __restrict__ fnv,
            float* __restrict__ corr, int base_ch) {
    int pos = blockIdx.x*256 + threadIdx.x;
    int g = blockIdx.y;
    if (pos >= S2_3) return;
    int x = pos / S2_2, rem = pos % S2_2, y = rem / S2, z = rem % S2;
    const float* fp = fpv + (size_t)g*64*S2_3;
    const float* fn = fnv + (size_t)g*64*S2_3;
    int   nidx[9];
    float nmask[9];
#pragma unroll
    for (int di = -1; di <= 1; ++di) {
        int xx = x + di; int xc = min(max(xx,0),S2-1); bool okx = (unsigned)xx < (unsigned)S2;
#pragma unroll
        for (int dj = -1; dj <= 1; ++dj) {
            int yy = y + dj; int yc = min(max(yy,0),S2-1);
            bool ok = okx && ((unsigned)yy < (unsigned)S2);
            nidx [(di+1)*3 + dj+1] = xc*S2_2 + yc*S2 + z;
            nmask[(di+1)*3 + dj+1] = ok ? 1.f : 0.f;
        }
    }
    float acc[9] = {0,0,0,0,0,0,0,0,0};
    for (int c = 0; c < 64; ++c) {
        float pc = fp[(size_t)c*S2_3 + pos];
        const float* fnc = fn + (size_t)c*S2_3;
#pragma unroll
        for (int s = 0; s < 9; ++s) acc[s] = fmaf(pc, fnc[nidx[s]]*nmask[s], acc[s]);
    }
    const float inv64 = 1.f/64.f;
#pragma unroll
    for (int k = 0; k < 3; ++k) {
        float zf = ((k==0 && z==S2-1) || (k==2 && z==0)) ? 0.f : inv64;
#pragma unroll
        for (int s = 0; s < 9; ++s)
            corr[(size_t)(g*54 + base_ch + k*9 + s)*S2_3 + pos] = acc[s]*zf;
    }
}

// =====================================================================
// generic 3x3x3 pad-1 conv, NIC -> 8, at S^3 (no bias; BN follows)
// =====================================================================
template<int NIC, int S_>
__global__ void __launch_bounds__(256)
conv3_kernel(const float* __restrict__ in, const float* __restrict__ w,
             float* __restrict__ out) {
    constexpr int SS = S_*S_, SSS = S_*S_*S_;
    int pos = blockIdx.x*256 + threadIdx.x;
    int g = blockIdx.y;
    if (pos >= SSS) return;
    int x = pos / SS, rem = pos % SS, y = rem / S_, z = rem % S_;
    float acc[8] = {0,0,0,0,0,0,0,0};
    for (int ic = 0; ic < NIC; ++ic) {
        const float* inc = in + (size_t)(g*NIC + ic)*SSS;
        float v[27];
#pragma unroll
        for (int dx = -1; dx <= 1; ++dx) {
            int xx = x + dx; int xc = min(max(xx,0),S_-1); bool okx = (unsigned)xx < (unsigned)S_;
#pragma unroll
            for (int dy = -1; dy <= 1; ++dy) {
                int yy = y + dy; int yc = min(max(yy,0),S_-1);
                bool oky = okx && ((unsigned)yy < (unsigned)S_);
#pragma unroll
                for (int dz = -1; dz <= 1; ++dz) {
                    int zz = z + dz; int zc = min(max(zz,0),S_-1);
                    bool ok = oky && ((unsigned)zz < (unsigned)S_);
                    float t = inc[xc*SS + yc*S_ + zc];
                    v[(dx+1)*9 + (dy+1)*3 + (dz+1)] = ok ? t : 0.f;
                }
            }
        }
#pragma unroll
        for (int oc = 0; oc < 8; ++oc) {
            const float* wr = w + (size_t)(oc*NIC + ic)*27;   // uniform -> s_load
#pragma unroll
            for (int t = 0; t < 27; ++t) acc[oc] = fmaf(v[t], wr[t], acc[oc]);
        }
    }
#pragma unroll
    for (int oc = 0; oc < 8; ++oc)
        out[(size_t)(g*8 + oc)*SSS + pos] = acc[oc];
}

// =====================================================================
// BN stats, two-stage. Stage A: (NBLK_STAT x 8ch) blocks, f64 partials.
// Stage B: 8 blocks reduce partials -> stats[ch*2]=mean, [ch*2+1]=rsqrt(var+eps)
// =====================================================================
__global__ void __launch_bounds__(256)
bn_part_kernel(const float* __restrict__ in, int npos, double* __restrict__ part) {
    int ch = blockIdx.y;
    int blk = blockIdx.x;
    int tid = threadIdx.x;
    double s = 0.0, ss = 0.0;
    for (int g = 0; g < NG; ++g) {
        const float* p = in + (size_t)(g*8 + ch)*npos;
        for (int i = blk*256 + tid; i < npos; i += NBLK_STAT*256) {
            double v = p[i]; s += v; ss += v*v;
        }
    }
    __shared__ double sd[256], sd2[256];
    sd[tid] = s; sd2[tid] = ss; __syncthreads();
    for (int o = 128; o > 0; o >>= 1) {
        if (tid < o) { sd[tid] += sd[tid+o]; sd2[tid] += sd2[tid+o]; }
        __syncthreads();
    }
    if (tid == 0) {
        part[((size_t)ch*NBLK_STAT + blk)*2    ] = sd[0];
        part[((size_t)ch*NBLK_STAT + blk)*2 + 1] = sd2[0];
    }
}

__global__ void __launch_bounds__(256)
bn_finish_kernel(const double* __restrict__ part, int npos, float* __restrict__ stats) {
    int ch = blockIdx.x;
    int tid = threadIdx.x;
    __shared__ double sd[256], sd2[256];
    sd[tid]  = part[((size_t)ch*NBLK_STAT + tid)*2];
    sd2[tid] = part[((size_t)ch*NBLK_STAT + tid)*2 + 1];
    __syncthreads();
    for (int o = 128; o > 0; o >>= 1) {
        if (tid < o) { sd[tid] += sd[tid+o]; sd2[tid] += sd2[tid+o]; }
        __syncthreads();
    }
    if (tid == 0) {
        double n = (double)npos * NG;
        double mean = sd[0]/n;
        double var  = sd2[0]/n - mean*mean;
        stats[ch*2]   = (float)mean;
        stats[ch*2+1] = (float)(1.0/sqrt(var + 1e-5));
    }
}

// =====================================================================
// fused BN + ReLU + x2 trilinear (align-corners-style) upsample 33^3 -> 66^3
// =====================================================================
__global__ void __launch_bounds__(256)
bn_relu_up_kernel(const float* __restrict__ in, const float* __restrict__ stats,
                  const float* __restrict__ gamma, const float* __restrict__ beta,
                  float* __restrict__ out) {
    int pos = blockIdx.x*256 + threadIdx.x;
    if (pos >= S1_3) return;
    int gc = blockIdx.y;           // g*8+ch
    int ch = gc & 7;
    int X = pos / S1_2, rem = pos % S1_2, Y = rem / S1, Z = rem % S1;
    const float scale = (float)(32.0/65.0);
    float sx = (float)X*scale, sy = (float)Y*scale, sz = (float)Z*scale;
    int x0 = (int)floorf(sx), y0 = (int)floorf(sy), z0 = (int)floorf(sz);
    float wx = sx - (float)x0, wy = sy - (float)y0, wz = sz - (float)z0;
    int x1 = min(x0+1, S2-1), y1 = min(y0+1, S2-1), z1 = min(z0+1, S2-1);
    float a = stats[ch*2+1]*gamma[ch];
    float c = beta[ch] - stats[ch*2]*a;
    const float* p = in + (size_t)gc*S2_3;
    auto val = [&](int xi, int yi, int zi) {
        float t = fmaf(p[xi*S2_2 + yi*S2 + zi], a, c);
        return t > 0.f ? t : 0.f;
    };
    float t00 = val(x0,y0,z0)*(1.f-wx) + val(x1,y0,z0)*wx;
    float t10 = val(x0,y1,z0)*(1.f-wx) + val(x1,y1,z0)*wx;
    float t01 = val(x0,y0,z1)*(1.f-wx) + val(x1,y0,z1)*wx;
    float t11 = val(x0,y1,z1)*(1.f-wx) + val(x1,y1,z1)*wx;
    float u0 = t00*(1.f-wy) + t10*wy;
    float u1 = t01*(1.f-wy) + t11*wy;
    out[(size_t)gc*S1_3 + pos] = u0*(1.f-wz) + u1*wz;
}

// =====================================================================
// fused BN + ReLU + 1x1x1 conv (+bias, *scale) -> helm channels
// =====================================================================
template<int NOC>
__global__ void __launch_bounds__(256)
outconv_kernel(const float* __restrict__ in, const float* __restrict__ stats,
               const float* __restrict__ gamma, const float* __restrict__ beta,
               const float* __restrict__ ow, const float* __restrict__ ob,
               const float* __restrict__ wscale, float extra,
               float* __restrict__ helm, int oc_off) {
    int pos = blockIdx.x*256 + threadIdx.x;
    int g = blockIdx.y;
    if (pos >= S1_3) return;
    float r[8];
#pragma unroll
    for (int ic = 0; ic < 8; ++ic) {
        float a = stats[ic*2+1]*gamma[ic];
        float c = beta[ic] - stats[ic*2]*a;
        float t = fmaf(in[(size_t)(g*8 + ic)*S1_3 + pos], a, c);
        r[ic] = t > 0.f ? t : 0.f;
    }
    float sc = wscale[0]*extra;
#pragma unroll
    for (int oc = 0; oc < NOC; ++oc) {
        float acc = ob[oc];
#pragma unroll
        for (int ic = 0; ic < 8; ++ic) acc = fmaf(r[ic], ow[oc*8 + ic], acc);
        helm[(size_t)(g*4 + oc_off + oc)*S1_3 + pos] = acc*sc;
    }
}

// =====================================================================
// velocity: helm (8,4,66^3) -> vel_phi, vel_vort, vel (8,3,64^3)
// =====================================================================
__global__ void __launch_bounds__(256)
velocity_kernel(const float* __restrict__ helm, float* __restrict__ vel,
                float* __restrict__ vphi, float* __restrict__ vvort) {
    int pos = blockIdx.x*256 + threadIdx.x;
    int g = blockIdx.y;
    if (pos >= S3_3) return;
    int x = pos / S3_2, rem = pos % S3_2, y = rem / S3, z = rem % S3;
    const float* H = helm + (size_t)g*4*S1_3;
    auto idx = [&](int c, int i, int j, int k) { return (size_t)c*S1_3 + i*S1_2 + j*S1 + k; };
    // phi (channel 0)
    float pu = 0.5f*(H[idx(0,x+1,y+1,z+2)] - H[idx(0,x+1,y+1,z  )]);
    float pv = 0.5f*(H[idx(0,x+1,y+2,z+1)] - H[idx(0,x+1,y  ,z+1)]);
    float pw = 0.5f*(H[idx(0,x+2,y+1,z+1)] - H[idx(0,x  ,y+1,z+1)]);
    // stream: s0=ch1, s1=ch2, s2=ch3
    float vu = 0.5f*( (H[idx(2,x+2,y+1,z+1)]-H[idx(2,x+1,y+1,z+1)]) - (H[idx(1,x+1,y+2,z+1)]-H[idx(1,x+1,y+1,z+1)])
                    + (H[idx(2,x+2,y+1,z  )]-H[idx(2,x+1,y+1,z  )]) - (H[idx(1,x+1,y+2,z  )]-H[idx(1,x+1,y+1,z  )]) );
    float vv = 0.5f*( (H[idx(1,x+1,y+1,z+2)]-H[idx(1,x+1,y+1,z+1)]) - (H[idx(3,x+2,y+1,z+1)]-H[idx(3,x+1,y+1,z+1)])
                    + (H[idx(1,x+1,y  ,z+2)]-H[idx(1,x+1,y  ,z+1)]) - (H[idx(3,x+2,y  ,z+1)]-H[idx(3,x+1,y  ,z+1)]) );
    float vw = 0.5f*( (H[idx(3,x+1,y+2,z+1)]-H[idx(3,x+1,y+1,z+1)]) - (H[idx(2,x+1,y+1,z+2)]-H[idx(2,x+1,y+1,z+1)])
                    + (H[idx(3,x  ,y+2,z+1)]-H[idx(3,x  ,y+1,z+1)]) - (H[idx(2,x  ,y+1,z+2)]-H[idx(2,x  ,y+1,z+1)]) );
    size_t o0 = (size_t)(g*3+0)*S3_3 + pos;
    size_t o1 = (size_t)(g*3+1)*S3_3 + pos;
    size_t o2 = (size_t)(g*3+2)*S3_3 + pos;
    vphi[o0] = pu;      vphi[o1] = pv;      vphi[o2] = pw;
    vvort[o0] = vu;     vvort[o1] = vv;     vvort[o2] = vw;
    vel[o0] = pu + vu;  vel[o1] = pv + vv;  vel[o2] = pw + vw;
}

// =====================================================================
// trilinear advection. BFECC variant samples (tex + 0.5*(tex - phi2)).
// =====================================================================
template<bool BFECC>
__global__ void __launch_bounds__(256)
advect_kernel(const float* __restrict__ f, const float* __restrict__ f2,
              const float* __restrict__ vel, float vsign,
              float* __restrict__ out) {
    int pos = blockIdx.x*256 + threadIdx.x;
    int g = blockIdx.y;
    if (pos >= S3_3) return;
    int x = pos / S3_2, rem = pos % S3_2, y = rem / S3, z = rem % S3;
    float px = (float)x - vsign*vel[(size_t)(g*3+2)*S3_3 + pos];
    float py = (float)y - vsign*vel[(size_t)(g*3+1)*S3_3 + pos];
    float pz = (float)z - vsign*vel[(size_t)(g*3+0)*S3_3 + pos];
    px = fminf(fmaxf(px, 0.f), 63.f);
    py = fminf(fmaxf(py, 0.f), 63.f);
    pz = fminf(fmaxf(pz, 0.f), 63.f);
    int x0 = (int)floorf(px), y0 = (int)floorf(py), z0 = (int)floorf(pz);
    int x1 = min(x0+1, S3-1), y1 = min(y0+1, S3-1), z1 = min(z0+1, S3-1);
    float fx = px - (float)x0, fy = py - (float)y0, fz = pz - (float)z0;
    int xo0 = x0*S3_2, xo1 = x1*S3_2, yo0 = y0*S3, yo1 = y1*S3;
    int i000 = xo0+yo0+z0, i100 = xo1+yo0+z0, i010 = xo0+yo1+z0, i110 = xo1+yo1+z0;
    int i001 = xo0+yo0+z1, i101 = xo1+yo0+z1, i011 = xo0+yo1+z1, i111 = xo1+yo1+z1;
    for (int c = 0; c < 8; ++c) {
        const float* fc  = f  + (size_t)(g*8 + c)*S3_3;
        const float* f2c = BFECC ? (f2 + (size_t)(g*8 + c)*S3_3) : nullptr;
        auto corner = [&](int i) {
            float t = fc[i];
            if (BFECC) { float p = f2c[i]; t = t + 0.5f*(t - p); }
            return t;
        };
        float g000 = corner(i000), g100 = corner(i100), g010 = corner(i010), g110 = corner(i110);
        float g001 = corner(i001), g101 = corner(i101), g011 = corner(i011), g111 = corner(i111);
        float r = ((g000*(1.f-fx) + g100*fx)*(1.f-fy) + (g010*(1.f-fx) + g110*fx)*fy)*(1.f-fz)
                + ((g001*(1.f-fx) + g101*fx)*(1.f-fy) + (g011*(1.f-fx) + g111*fx)*fy)*fz;
        out[(size_t)(g*8 + c)*S3_3 + pos] = r;
    }
}

// =====================================================================
// LayerNorm(64ch) + Linear(64,64) + GELU(exact) + Linear(64,64) + residual
// =====================================================================
__global__ void __launch_bounds__(256)
ln_mlp_kernel(const float* __restrict__ pred,
              const float* __restrict__ lng, const float* __restrict__ lnb,
              const float* __restrict__ w1, const float* __restrict__ b1,
              const float* __restrict__ w2, const float* __restrict__ b2,
              float* __restrict__ xout) {
    int pos = blockIdx.x*256 + threadIdx.x;
    if (pos >= S3_3) return;
    // pass 1: mean / var
    float s = 0.f, ss = 0.f;
    for (int i = 0; i < 64; ++i) {
        float v = pred[(size_t)i*S3_3 + pos];
        s += v; ss += v*v;
    }
    float mu = s*(1.f/64.f);
    float var = ss*(1.f/64.f) - mu*mu;
    float rs = rsqrtf(var + 1e-5f);
    // pass 2: y1 = LN(h) @ w1 + b1
    float y1[64];
#pragma unroll
    for (int j = 0; j < 64; ++j) y1[j] = b1[j];
    for (int i = 0; i < 64; ++i) {
        float v = pred[(size_t)i*S3_3 + pos];
        float hn = (v - mu)*rs*lng[i] + lnb[i];
        const float* wr = w1 + i*64;          // uniform -> s_load_dwordx
#pragma unroll
        for (int j = 0; j < 64; ++j) y1[j] = fmaf(hn, wr[j], y1[j]);
    }
#pragma unroll
    for (int j = 0; j < 64; ++j) {
        float t = y1[j];
        y1[j] = 0.5f*t*(1.f + erff(t*0.70710678118654752f));
    }
    // pass 3: out = pred + y1 @ w2 + b2
    for (int c = 0; c < 64; ++c) {
        float acc = b2[c];
#pragma unroll
        for (int j = 0; j < 64; ++j) acc = fmaf(y1[j], w2[j*64 + c], acc);
        xout[(size_t)c*S3_3 + pos] = pred[(size_t)c*S3_3 + pos] + acc;
    }
}

// =====================================================================
extern "C" void kernel_launch(void* const* d_in, const int* in_sizes, int n_in,
                              void* d_out, int out_size, void* d_ws, size_t ws_size,
                              hipStream_t stream) {
    const float* prev       = (const float*)d_in[0];
    const float* nxt        = (const float*)d_in[1];
    const float* tex        = (const float*)d_in[2];
    const float* mask       = (const float*)d_in[3];
    const float* boundary   = (const float*)d_in[4];
    const float* enc_w      = (const float*)d_in[5];
    const float* enc_b      = (const float*)d_in[6];
    const float* phi_c1_w   = (const float*)d_in[7];
    const float* phi_bn1_g  = (const float*)d_in[8];
    const float* phi_bn1_b  = (const float*)d_in[9];
    const float* phi_c2_w   = (const float*)d_in[10];
    const float* phi_bn2_g  = (const float*)d_in[11];
    const float* phi_bn2_b  = (const float*)d_in[12];
    const float* phi_out_w  = (const float*)d_in[13];
    const float* phi_out_b  = (const float*)d_in[14];
    const float* vort_c1_w  = (const float*)d_in[15];
    const float* vort_bn1_g = (const float*)d_in[16];
    const float* vort_bn1_b = (const float*)d_in[17];
    const float* vort_c2_w  = (const float*)d_in[18];
    const float* vort_bn2_g = (const float*)d_in[19];
    const float* vort_bn2_b = (const float*)d_in[20];
    const float* vort_out_w = (const float*)d_in[21];
    const float* vort_out_b = (const float*)d_in[22];
    const float* phi_weight = (const float*)d_in[23];
    const float* vort_weight= (const float*)d_in[24];
    const float* ln_g       = (const float*)d_in[25];
    const float* ln_b       = (const float*)d_in[26];
    const float* ff_w1      = (const float*)d_in[27];
    const float* ff_b1      = (const float*)d_in[28];
    const float* ff_w2      = (const float*)d_in[29];
    const float* ff_b2      = (const float*)d_in[30];

    float* ws  = (float*)d_ws;
    float* out = (float*)d_out;

    float* w_corr  = ws + CORR_OFF;
    float* w_c1p   = ws + C1P_OFF;
    float* w_c1v   = ws + C1V_OFF;
    float* w_stats = ws + STATS_OFF;
    float* w_big   = ws;                 // reused: conv2_phi / conv2_vort / phi1 / pred

    // d_out regions used as early scratch (fully rewritten before return):
    float* o_x    = out + X_OFF;         // f_nm / up_phi / phi2
    float* o_helm = out + HELM_OFF;
    float* o_vel  = out + VEL_OFF;       // f_pm,f_pb / up_vort (vel written later)
    float* o_vphi = out + VPHI_OFF;
    float* o_vvort= out + VVORT_OFF;

    // BN partials: 32 KB at the start of the X region (dead at all 4 stat points)
    double* d_part = (double*)o_x;

    dim3 b256(256);
    dim3 gs2((S2_3 + 255)/256, NG);      // 141 x 8
    dim3 gs1((S1_3 + 255)/256, NG);      // 1124 x 8
    dim3 gs1c((S1_3 + 255)/256, NG*CG);  // 1124 x 64
    dim3 gs3((S3_3 + 255)/256, NG);      // 1024 x 8
    dim3 gmlp((S3_3 + 255)/256);         // 1024
    dim3 gstat(NBLK_STAT, 8);            // 256 x 8

    // ---- encoder + correlation ----
    enc_kernel<<<gs2, b256, 0, stream>>>(nxt,  mask,     enc_w, enc_b, o_x);   // f_nm
    enc_kernel<<<gs2, b256, 0, stream>>>(prev, mask,     enc_w, enc_b, o_vel); // f_pm
    corr_kernel<<<gs2, b256, 0, stream>>>(o_vel, o_x, w_corr, 0);
    enc_kernel<<<gs2, b256, 0, stream>>>(prev, boundary, enc_w, enc_b, o_vel); // f_pb
    corr_kernel<<<gs2, b256, 0, stream>>>(o_vel, o_x, w_corr, 27);

    // ---- conv1 (54->8, 33^3) + BN stats (partials in dead X region) ----
    conv3_kernel<54,33><<<gs2, b256, 0, stream>>>(w_corr, phi_c1_w,  w_c1p);
    conv3_kernel<54,33><<<gs2, b256, 0, stream>>>(w_corr, vort_c1_w, w_c1v);
    bn_part_kernel  <<<gstat, b256, 0, stream>>>(w_c1p, S2_3, d_part);
    bn_finish_kernel<<<8,     b256, 0, stream>>>(d_part, S2_3, w_stats + 0);
    bn_part_kernel  <<<gstat, b256, 0, stream>>>(w_c1v, S2_3, d_part);
    bn_finish_kernel<<<8,     b256, 0, stream>>>(d_part, S2_3, w_stats + 16);

    // ---- BN+ReLU+upsample to 66^3 (into dead d_out scratch) ----
    bn_relu_up_kernel<<<gs1c, b256, 0, stream>>>(w_c1p, w_stats + 0,  phi_bn1_g,  phi_bn1_b,  o_x);
    bn_relu_up_kernel<<<gs1c, b256, 0, stream>>>(w_c1v, w_stats + 16, vort_bn1_g, vort_bn1_b, o_vel);

    // ---- conv2 + BN stats + out-conv, phi then vort (sharing ws+0) ----
    conv3_kernel<8,66><<<gs1, b256, 0, stream>>>(o_x, phi_c2_w, w_big);
    bn_part_kernel  <<<gstat, b256, 0, stream>>>(w_big, S1_3, d_part);   // X dead (up_phi consumed)
    bn_finish_kernel<<<8,     b256, 0, stream>>>(d_part, S1_3, w_stats + 32);
    outconv_kernel<1><<<gs1, b256, 0, stream>>>(w_big, w_stats + 32, phi_bn2_g, phi_bn2_b,
                                                phi_out_w, phi_out_b, phi_weight, 1.0f,
                                                o_helm, 0);
    conv3_kernel<8,66><<<gs1, b256, 0, stream>>>(o_vel, vort_c2_w, w_big);
    bn_part_kernel  <<<gstat, b256, 0, stream>>>(w_big, S1_3, d_part);   // X still dead
    bn_finish_kernel<<<8,     b256, 0, stream>>>(d_part, S1_3, w_stats + 48);
    outconv_kernel<3><<<gs1, b256, 0, stream>>>(w_big, w_stats + 48, vort_bn2_g, vort_bn2_b,
                                                vort_out_w, vort_out_b, vort_weight, 66.0f,
                                                o_helm, 1);

    // ---- velocities (writes final vel / vel_phi / vel_vort) ----
    velocity_kernel<<<gs3, b256, 0, stream>>>(o_helm, o_vel, o_vphi, o_vvort);

    // ---- BFECC advection ----
    advect_kernel<false><<<gs3, b256, 0, stream>>>(tex,   nullptr, o_vel,  1.f, w_big); // phi1 -> ws
    advect_kernel<false><<<gs3, b256, 0, stream>>>(w_big, nullptr, o_vel, -1.f, o_x);   // phi2 -> x region
    advect_kernel<true ><<<gs3, b256, 0, stream>>>(tex,   o_x,     o_vel,  1.f, w_big); // pred -> ws

    // ---- LayerNorm + MLP + residual (writes final x) ----
    ln_mlp_kernel<<<gmlp, b256, 0, stream>>>(w_big, ln_g, ln_b, ff_w1, ff_b1, ff_w2, ff_b2, o_x);
}

// Round 10
// 2649.826 us; speedup vs baseline: 1.6112x; 1.0883x over previous
//
#include <hip/hip_runtime.h>
#include <math.h>

// ---------------- problem geometry ----------------
constexpr int S1 = 66, S1_2 = S1*S1, S1_3 = S1*S1*S1;   // 4356, 287496
constexpr int S2 = 33, S2_2 = S2*S2, S2_3 = S2*S2*S2;   // 1089, 35937
constexpr int S3 = 64, S3_2 = S3*S3, S3_3 = S3*S3*S3;   // 4096, 262144
constexpr int NG = 8;    // groups
constexpr int CG = 8;    // channels per group
constexpr int D  = 64;   // total channels

// ---------------- d_out layout (floats) ----------------
constexpr size_t X_OFF     = 0;                                   // x: 16,777,216
constexpr size_t HELM_OFF  = (size_t)D*S3_3;                      // helm: 9,199,872... offset
constexpr size_t VEL_OFF   = HELM_OFF + (size_t)NG*4*S1_3;
constexpr size_t VPHI_OFF  = VEL_OFF  + (size_t)NG*3*S3_3;
constexpr size_t VVORT_OFF = VPHI_OFF + (size_t)NG*3*S3_3;

// ---------------- d_ws layout (floats) ----------------
constexpr size_t CORR_OFF  = 0;                                   // 8*54*33^3
constexpr size_t C1P_OFF   = CORR_OFF + (size_t)NG*54*S2_3;
constexpr size_t C1V_OFF   = C1P_OFF  + (size_t)NG*8*S2_3;
constexpr size_t STATS_OFF = C1V_OFF  + (size_t)NG*8*S2_3;
// ws+0 reused later for: conv2_phi, conv2_vort, phi1, pred

// BN partials (32 KB) at the start of the X region of d_out (dead at all 4
// stat points; see round-5 liveness audit). NOT vel_phi (round-4 bug).
constexpr int NBLK_STAT = 256;

// =====================================================================
// encoder
// =====================================================================
__global__ void __launch_bounds__(256)
enc_kernel(const float* __restrict__ in, const float* __restrict__ msk,
           const float* __restrict__ w,  const float* __restrict__ b,
           float* __restrict__ out) {
    int pos = blockIdx.x*256 + threadIdx.x;
    int g = blockIdx.y;
    if (pos >= S2_3) return;
    int x = pos / S2_2, rem = pos % S2_2, y = rem / S2, z = rem % S2;
    int ib = 2*x*S1_2 + 2*y*S1 + 2*z;
    float mv[8];
#pragma unroll
    for (int c = 0; c < 8; ++c) {
        int dx = c>>2, dy = (c>>1)&1, dz = c&1;
        mv[c] = msk[ib + dx*S1_2 + dy*S1 + dz];
    }
    float mi[64];
#pragma unroll
    for (int ic = 0; ic < 8; ++ic) {
        const float* inc = in + (size_t)(g*CG + ic)*S1_3 + ib;
#pragma unroll
        for (int c = 0; c < 8; ++c) {
            int dx = c>>2, dy = (c>>1)&1, dz = c&1;
            mi[ic*8 + c] = inc[dx*S1_2 + dy*S1 + dz] * mv[c];
        }
    }
    for (int oc = 0; oc < 64; ++oc) {
        float acc = b[oc];
#pragma unroll
        for (int t = 0; t < 64; ++t) acc = fmaf(mi[t], w[oc*64 + t], acc);
        out[(size_t)(g*64 + oc)*S2_3 + pos] = acc;
    }
}

// =====================================================================
// correlation half
// =====================================================================
__global__ void __launch_bounds__(256)
corr_kernel(const float* __restrict__ fpv, const float* __restrict__ fnv,
            float* __restrict__ corr, int base_ch) {
    int pos = blockIdx.x*256 + threadIdx.x;
    int g = blockIdx.y;
    if (pos >= S2_3) return;
    int x = pos / S2_2, rem = pos % S2_2, y = rem / S2, z = rem % S2;
    const float* fp = fpv + (size_t)g*64*S2_3;
    const float* fn = fnv + (size_t)g*64*S2_3;
    int   nidx[9];
    float nmask[9];
#pragma unroll
    for (int di = -1; di <= 1; ++di) {
        int xx = x + di; int xc = min(max(xx,0),S2-1); bool okx = (unsigned)xx < (unsigned)S2;
#pragma unroll
        for (int dj = -1; dj <= 1; ++dj) {
            int yy = y + dj; int yc = min(max(yy,0),S2-1);
            bool ok = okx && ((unsigned)yy < (unsigned)S2);
            nidx [(di+1)*3 + dj+1] = xc*S2_2 + yc*S2 + z;
            nmask[(di+1)*3 + dj+1] = ok ? 1.f : 0.f;
        }
    }
    float acc[9] = {0,0,0,0,0,0,0,0,0};
    for (int c = 0; c < 64; ++c) {
        float pc = fp[(size_t)c*S2_3 + pos];
        const float* fnc = fn + (size_t)c*S2_3;
#pragma unroll
        for (int s = 0; s < 9; ++s) acc[s] = fmaf(pc, fnc[nidx[s]]*nmask[s], acc[s]);
    }
    const float inv64 = 1.f/64.f;
#pragma unroll
    for (int k = 0; k < 3; ++k) {
        float zf = ((k==0 && z==S2-1) || (k==2 && z==0)) ? 0.f : inv64;
#pragma unroll
        for (int s = 0; s < 9; ++s)
            corr[(size_t)(g*54 + base_ch + k*9 + s)*S2_3 + pos] = acc[s]*zf;
    }
}

// =====================================================================
// FUSED conv1: 54ch -> 8 (phi) + 8 (vort) at 33^3, LDS-tiled, pipelined.
// Round-8 profile: 2x conv3<54,33> = 800us, VALUBusy 29.6% (latency-bound
// on 1458 scattered global loads/thread). This kernel: one input pass,
// 27x LDS reuse, next-channel loads hidden under compute (G15/T14).
// Tile: 4x8x8 outputs/block; halo tile 6x10x10 staged with z-stride 12
// (ty*12+tz -> exact 2-way bank aliasing = free, m136).
// =====================================================================
constexpr int TLX = 4, TLY = 8, TLZ = 8;
constexpr int NTX = 9, NTY = 5, NTZ = 5;          // 36,40,40 cover 33
constexpr int HLX = TLX+2, HLY = TLY+2, HLZ = TLZ+2;  // 6,10,10
constexpr int LZP = 12;                            // padded z-stride
constexpr int TILE_N = HLX*HLY*LZP;                // 720 floats

__global__ void __launch_bounds__(256)
conv1_fused_kernel(const float* __restrict__ in,
                   const float* __restrict__ wp,  // phi  (8,54,3,3,3)
                   const float* __restrict__ wv,  // vort (8,54,3,3,3)
                   float* __restrict__ outp, float* __restrict__ outv) {
    __shared__ float tile[TILE_N];
    int tid = threadIdx.x;
    int g = blockIdx.y;
    int b = blockIdx.x;
    int bx = b / (NTY*NTZ), brem = b % (NTY*NTZ), by = brem / NTZ, bz = brem % NTZ;
    int X0 = bx*TLX, Y0 = by*TLY, Z0 = bz*TLZ;
    int tx = tid >> 6, ty = (tid >> 3) & 7, tz = tid & 7;   // 4x8x8
    int gx = X0 + tx, gy = Y0 + ty, gz = Z0 + tz;
    bool valid = (gx < S2) && (gy < S2) && (gz < S2);
    const float* gbase = in + (size_t)g*54*S2_3;

    auto load_ch = [&](int ic, float r[3]) {
        const float* base = gbase + (size_t)ic*S2_3;
        int k = 0;
        for (int i = tid; i < TILE_N; i += 256, ++k) {
            int lx = i / (HLY*LZP), lr = i % (HLY*LZP), ly = lr / LZP, lz = lr % LZP;
            int ax = X0-1+lx, ay = Y0-1+ly, az = Z0-1+lz;
            bool ok = (unsigned)ax < (unsigned)S2 && (unsigned)ay < (unsigned)S2
                   && (unsigned)az < (unsigned)S2;
            r[k] = ok ? base[ax*S2_2 + ay*S2 + az] : 0.f;
        }
    };

    float accP[8] = {0,0,0,0,0,0,0,0};
    float accV[8] = {0,0,0,0,0,0,0,0};
    float r[3];
    load_ch(0, r);

    for (int ic = 0; ic < 54; ++ic) {
        __syncthreads();                       // prev compute done; LDS free
        {   int k = 0;
            for (int i = tid; i < TILE_N; i += 256, ++k) tile[i] = r[k];
        }
        float rn[3] = {0.f, 0.f, 0.f};
        if (ic + 1 < 54) load_ch(ic + 1, rn);  // in flight under compute
        __syncthreads();                       // LDS visible

        float v[27];
#pragma unroll
        for (int dx = 0; dx < 3; ++dx)
#pragma unroll
            for (int dy = 0; dy < 3; ++dy)
#pragma unroll
                for (int dz = 0; dz < 3; ++dz)
                    v[dx*9 + dy*3 + dz] =
                        tile[(tx+dx)*(HLY*LZP) + (ty+dy)*LZP + (tz+dz)];
#pragma unroll
        for (int oc = 0; oc < 8; ++oc) {
            const float* wpr = wp + (size_t)(oc*54 + ic)*27;  // uniform -> s_load
            const float* wvr = wv + (size_t)(oc*54 + ic)*27;
#pragma unroll
            for (int t = 0; t < 27; ++t) {
                accP[oc] = fmaf(v[t], wpr[t], accP[oc]);
                accV[oc] = fmaf(v[t], wvr[t], accV[oc]);
            }
        }
        r[0] = rn[0]; r[1] = rn[1]; r[2] = rn[2];
    }

    if (valid) {
        int pos = gx*S2_2 + gy*S2 + gz;
#pragma unroll
        for (int oc = 0; oc < 8; ++oc) {
            outp[(size_t)(g*8 + oc)*S2_3 + pos] = accP[oc];
            outv[(size_t)(g*8 + oc)*S2_3 + pos] = accV[oc];
        }
    }
}

// =====================================================================
// generic 3x3x3 pad-1 conv, NIC -> 8 (still used for the 8->8 @66^3 convs)
// =====================================================================
template<int NIC, int S_>
__global__ void __launch_bounds__(256)
conv3_kernel(const float* __restrict__ in, const float* __restrict__ w,
             float* __restrict__ out) {
    constexpr int SS = S_*S_, SSS = S_*S_*S_;
    int pos = blockIdx.x*256 + threadIdx.x;
    int g = blockIdx.y;
    if (pos >= SSS) return;
    int x = pos / SS, rem = pos % SS, y = rem / S_, z = rem % S_;
    float acc[8] = {0,0,0,0,0,0,0,0};
    for (int ic = 0; ic < NIC; ++ic) {
        const float* inc = in + (size_t)(g*NIC + ic)*SSS;
        float v[27];
#pragma unroll
        for (int dx = -1; dx <= 1; ++dx) {
            int xx = x + dx; int xc = min(max(xx,0),S_-1); bool okx = (unsigned)xx < (unsigned)S_;
#pragma unroll
            for (int dy = -1; dy <= 1; ++dy) {
                int yy = y + dy; int yc = min(max(yy,0),S_-1);
                bool oky = okx && ((unsigned)yy < (unsigned)S_);
#pragma unroll
                for (int dz = -1; dz <= 1; ++dz) {
                    int zz = z + dz; int zc = min(max(zz,0),S_-1);
                    bool ok = oky && ((unsigned)zz < (unsigned)S_);
                    float t = inc[xc*SS + yc*S_ + zc];
                    v[(dx+1)*9 + (dy+1)*3 + (dz+1)] = ok ? t : 0.f;
                }
            }
        }
#pragma unroll
        for (int oc = 0; oc < 8; ++oc) {
            const float* wr = w + (size_t)(oc*NIC + ic)*27;
#pragma unroll
            for (int t = 0; t < 27; ++t) acc[oc] = fmaf(v[t], wr[t], acc[oc]);
        }
    }
#pragma unroll
    for (int oc = 0; oc < 8; ++oc)
        out[(size_t)(g*8 + oc)*SSS + pos] = acc[oc];
}

// =====================================================================
// BN stats, two-stage
// =====================================================================
__global__ void __launch_bounds__(256)
bn_part_kernel(const float* __restrict__ in, int npos, double* __restrict__ part) {
    int ch = blockIdx.y;
    int blk = blockIdx.x;
    int tid = threadIdx.x;
    double s = 0.0, ss = 0.0;
    for (int g = 0; g < NG; ++g) {
        const float* p = in + (size_t)(g*8 + ch)*npos;
        for (int i = blk*256 + tid; i < npos; i += NBLK_STAT*256) {
            double v = p[i]; s += v; ss += v*v;
        }
    }
    __shared__ double sd[256], sd2[256];
    sd[tid] = s; sd2[tid] = ss; __syncthreads();
    for (int o = 128; o > 0; o >>= 1) {
        if (tid < o) { sd[tid] += sd[tid+o]; sd2[tid] += sd2[tid+o]; }
        __syncthreads();
    }
    if (tid == 0) {
        part[((size_t)ch*NBLK_STAT + blk)*2    ] = sd[0];
        part[((size_t)ch*NBLK_STAT + blk)*2 + 1] = sd2[0];
    }
}

__global__ void __launch_bounds__(256)
bn_finish_kernel(const double* __restrict__ part, int npos, float* __restrict__ stats) {
    int ch = blockIdx.x;
    int tid = threadIdx.x;
    __shared__ double sd[256], sd2[256];
    sd[tid]  = part[((size_t)ch*NBLK_STAT + tid)*2];
    sd2[tid] = part[((size_t)ch*NBLK_STAT + tid)*2 + 1];
    __syncthreads();
    for (int o = 128; o > 0; o >>= 1) {
        if (tid < o) { sd[tid] += sd[tid+o]; sd2[tid] += sd2[tid+o]; }
        __syncthreads();
    }
    if (tid == 0) {
        double n = (double)npos * NG;
        double mean = sd[0]/n;
        double var  = sd2[0]/n - mean*mean;
        stats[ch*2]   = (float)mean;
        stats[ch*2+1] = (float)(1.0/sqrt(var + 1e-5));
    }
}

// =====================================================================
// fused BN + ReLU + x2 trilinear upsample 33^3 -> 66^3
// =====================================================================
__global__ void __launch_bounds__(256)
bn_relu_up_kernel(const float* __restrict__ in, const float* __restrict__ stats,
                  const float* __restrict__ gamma, const float* __restrict__ beta,
                  float* __restrict__ out) {
    int pos = blockIdx.x*256 + threadIdx.x;
    if (pos >= S1_3) return;
    int gc = blockIdx.y;           // g*8+ch
    int ch = gc & 7;
    int X = pos / S1_2, rem = pos % S1_2, Y = rem / S1, Z = rem % S1;
    const float scale = (float)(32.0/65.0);
    float sx = (float)X*scale, sy = (float)Y*scale, sz = (float)Z*scale;
    int x0 = (int)floorf(sx), y0 = (int)floorf(sy), z0 = (int)floorf(sz);
    float wx = sx - (float)x0, wy = sy - (float)y0, wz = sz - (float)z0;
    int x1 = min(x0+1, S2-1), y1 = min(y0+1, S2-1), z1 = min(z0+1, S2-1);
    float a = stats[ch*2+1]*gamma[ch];
    float c = beta[ch] - stats[ch*2]*a;
    const float* p = in + (size_t)gc*S2_3;
    auto val = [&](int xi, int yi, int zi) {
        float t = fmaf(p[xi*S2_2 + yi*S2 + zi], a, c);
        return t > 0.f ? t : 0.f;
    };
    float t00 = val(x0,y0,z0)*(1.f-wx) + val(x1,y0,z0)*wx;
    float t10 = val(x0,y1,z0)*(1.f-wx) + val(x1,y1,z0)*wx;
    float t01 = val(x0,y0,z1)*(1.f-wx) + val(x1,y0,z1)*wx;
    float t11 = val(x0,y1,z1)*(1.f-wx) + val(x1,y1,z1)*wx;
    float u0 = t00*(1.f-wy) + t10*wy;
    float u1 = t01*(1.f-wy) + t11*wy;
    out[(size_t)gc*S1_3 + pos] = u0*(1.f-wz) + u1*wz;
}

// =====================================================================
// fused BN + ReLU + 1x1x1 conv -> helm channels
// =====================================================================
template<int NOC>
__global__ void __launch_bounds__(256)
outconv_kernel(const float* __restrict__ in, const float* __restrict__ stats,
               const float* __restrict__ gamma, const float* __restrict__ beta,
               const float* __restrict__ ow, const float* __restrict__ ob,
               const float* __restrict__ wscale, float extra,
               float* __restrict__ helm, int oc_off) {
    int pos = blockIdx.x*256 + threadIdx.x;
    int g = blockIdx.y;
    if (pos >= S1_3) return;
    float r[8];
#pragma unroll
    for (int ic = 0; ic < 8; ++ic) {
        float a = stats[ic*2+1]*gamma[ic];
        float c = beta[ic] - stats[ic*2]*a;
        float t = fmaf(in[(size_t)(g*8 + ic)*S1_3 + pos], a, c);
        r[ic] = t > 0.f ? t : 0.f;
    }
    float sc = wscale[0]*extra;
#pragma unroll
    for (int oc = 0; oc < NOC; ++oc) {
        float acc = ob[oc];
#pragma unroll
        for (int ic = 0; ic < 8; ++ic) acc = fmaf(r[ic], ow[oc*8 + ic], acc);
        helm[(size_t)(g*4 + oc_off + oc)*S1_3 + pos] = acc*sc;
    }
}

// =====================================================================
// velocity
// =====================================================================
__global__ void __launch_bounds__(256)
velocity_kernel(const float* __restrict__ helm, float* __restrict__ vel,
                float* __restrict__ vphi, float* __restrict__ vvort) {
    int pos = blockIdx.x*256 + threadIdx.x;
    int g = blockIdx.y;
    if (pos >= S3_3) return;
    int x = pos / S3_2, rem = pos % S3_2, y = rem / S3, z = rem % S3;
    const float* H = helm + (size_t)g*4*S1_3;
    auto idx = [&](int c, int i, int j, int k) { return (size_t)c*S1_3 + i*S1_2 + j*S1 + k; };
    float pu = 0.5f*(H[idx(0,x+1,y+1,z+2)] - H[idx(0,x+1,y+1,z  )]);
    float pv = 0.5f*(H[idx(0,x+1,y+2,z+1)] - H[idx(0,x+1,y  ,z+1)]);
    float pw = 0.5f*(H[idx(0,x+2,y+1,z+1)] - H[idx(0,x  ,y+1,z+1)]);
    float vu = 0.5f*( (H[idx(2,x+2,y+1,z+1)]-H[idx(2,x+1,y+1,z+1)]) - (H[idx(1,x+1,y+2,z+1)]-H[idx(1,x+1,y+1,z+1)])
                    + (H[idx(2,x+2,y+1,z  )]-H[idx(2,x+1,y+1,z  )]) - (H[idx(1,x+1,y+2,z  )]-H[idx(1,x+1,y+1,z  )]) );
    float vv = 0.5f*( (H[idx(1,x+1,y+1,z+2)]-H[idx(1,x+1,y+1,z+1)]) - (H[idx(3,x+2,y+1,z+1)]-H[idx(3,x+1,y+1,z+1)])
                    + (H[idx(1,x+1,y  ,z+2)]-H[idx(1,x+1,y  ,z+1)]) - (H[idx(3,x+2,y  ,z+1)]-H[idx(3,x+1,y  ,z+1)]) );
    float vw = 0.5f*( (H[idx(3,x+1,y+2,z+1)]-H[idx(3,x+1,y+1,z+1)]) - (H[idx(2,x+1,y+1,z+2)]-H[idx(2,x+1,y+1,z+1)])
                    + (H[idx(3,x  ,y+2,z+1)]-H[idx(3,x  ,y+1,z+1)]) - (H[idx(2,x  ,y+1,z+2)]-H[idx(2,x  ,y+1,z+1)]) );
    size_t o0 = (size_t)(g*3+0)*S3_3 + pos;
    size_t o1 = (size_t)(g*3+1)*S3_3 + pos;
    size_t o2 = (size_t)(g*3+2)*S3_3 + pos;
    vphi[o0] = pu;      vphi[o1] = pv;      vphi[o2] = pw;
    vvort[o0] = vu;     vvort[o1] = vv;     vvort[o2] = vw;
    vel[o0] = pu + vu;  vel[o1] = pv + vv;  vel[o2] = pw + vw;
}

// =====================================================================
// trilinear advection
// =====================================================================
template<bool BFECC>
__global__ void __launch_bounds__(256)
advect_kernel(const float* __restrict__ f, const float* __restrict__ f2,
              const float* __restrict__ vel, float vsign,
              float* __restrict__ out) {
    int pos = blockIdx.x*256 + threadIdx.x;
    int g = blockIdx.y;
    if (pos >= S3_3) return;
    int x = pos / S3_2, rem = pos % S3_2, y = rem / S3, z = rem % S3;
    float px = (float)x - vsign*vel[(size_t)(g*3+2)*S3_3 + pos];
    float py = (float)y - vsign*vel[(size_t)(g*3+1)*S3_3 + pos];
    float pz = (float)z - vsign*vel[(size_t)(g*3+0)*S3_3 + pos];
    px = fminf(fmaxf(px, 0.f), 63.f);
    py = fminf(fmaxf(py, 0.f), 63.f);
    pz = fminf(fmaxf(pz, 0.f), 63.f);
    int x0 = (int)floorf(px), y0 = (int)floorf(py), z0 = (int)floorf(pz);
    int x1 = min(x0+1, S3-1), y1 = min(y0+1, S3-1), z1 = min(z0+1, S3-1);
    float fx = px - (float)x0, fy = py - (float)y0, fz = pz - (float)z0;
    int xo0 = x0*S3_2, xo1 = x1*S3_2, yo0 = y0*S3, yo1 = y1*S3;
    int i000 = xo0+yo0+z0, i100 = xo1+yo0+z0, i010 = xo0+yo1+z0, i110 = xo1+yo1+z0;
    int i001 = xo0+yo0+z1, i101 = xo1+yo0+z1, i011 = xo0+yo1+z1, i111 = xo1+yo1+z1;
    for (int c = 0; c < 8; ++c) {
        const float* fc  = f  + (size_t)(g*8 + c)*S3_3;
        const float* f2c = BFECC ? (f2 + (size_t)(g*8 + c)*S3_3) : nullptr;
        auto corner = [&](int i) {
            float t = fc[i];
            if (BFECC) { float p = f2c[i]; t = t + 0.5f*(t - p); }
            return t;
        };
        float g000 = corner(i000), g100 = corner(i100), g010 = corner(i010), g110 = corner(i110);
        float g001 = corner(i001), g101 = corner(i101), g011 = corner(i011), g111 = corner(i111);
        float r = ((g000*(1.f-fx) + g100*fx)*(1.f-fy) + (g010*(1.f-fx) + g110*fx)*fy)*(1.f-fz)
                + ((g001*(1.f-fx) + g101*fx)*(1.f-fy) + (g011*(1.f-fx) + g111*fx)*fy)*fz;
        out[(size_t)(g*8 + c)*S3_3 + pos] = r;
    }
}

// =====================================================================
// LayerNorm + MLP + residual
// =====================================================================
__global__ void __launch_bounds__(256)
ln_mlp_kernel(const float* __restrict__ pred,
              const float* __restrict__ lng, const float* __restrict__ lnb,
              const float* __restrict__ w1, const float* __restrict__ b1,
              const float* __restrict__ w2, const float* __restrict__ b2,
              float* __restrict__ xout) {
    int pos = blockIdx.x*256 + threadIdx.x;
    if (pos >= S3_3) return;
    float s = 0.f, ss = 0.f;
    for (int i = 0; i < 64; ++i) {
        float v = pred[(size_t)i*S3_3 + pos];
        s += v; ss += v*v;
    }
    float mu = s*(1.f/64.f);
    float var = ss*(1.f/64.f) - mu*mu;
    float rs = rsqrtf(var + 1e-5f);
    float y1[64];
#pragma unroll
    for (int j = 0; j < 64; ++j) y1[j] = b1[j];
    for (int i = 0; i < 64; ++i) {
        float v = pred[(size_t)i*S3_3 + pos];
        float hn = (v - mu)*rs*lng[i] + lnb[i];
        const float* wr = w1 + i*64;
#pragma unroll
        for (int j = 0; j < 64; ++j) y1[j] = fmaf(hn, wr[j], y1[j]);
    }
#pragma unroll
    for (int j = 0; j < 64; ++j) {
        float t = y1[j];
        y1[j] = 0.5f*t*(1.f + erff(t*0.70710678118654752f));
    }
    for (int c = 0; c < 64; ++c) {
        float acc = b2[c];
#pragma unroll
        for (int j = 0; j < 64; ++j) acc = fmaf(y1[j], w2[j*64 + c], acc);
        xout[(size_t)c*S3_3 + pos] = pred[(size_t)c*S3_3 + pos] + acc;
    }
}

// =====================================================================
extern "C" void kernel_launch(void* const* d_in, const int* in_sizes, int n_in,
                              void* d_out, int out_size, void* d_ws, size_t ws_size,
                              hipStream_t stream) {
    const float* prev       = (const float*)d_in[0];
    const float* nxt        = (const float*)d_in[1];
    const float* tex        = (const float*)d_in[2];
    const float* mask       = (const float*)d_in[3];
    const float* boundary   = (const float*)d_in[4];
    const float* enc_w      = (const float*)d_in[5];
    const float* enc_b      = (const float*)d_in[6];
    const float* phi_c1_w   = (const float*)d_in[7];
    const float* phi_bn1_g  = (const float*)d_in[8];
    const float* phi_bn1_b  = (const float*)d_in[9];
    const float* phi_c2_w   = (const float*)d_in[10];
    const float* phi_bn2_g  = (const float*)d_in[11];
    const float* phi_bn2_b  = (const float*)d_in[12];
    const float* phi_out_w  = (const float*)d_in[13];
    const float* phi_out_b  = (const float*)d_in[14];
    const float* vort_c1_w  = (const float*)d_in[15];
    const float* vort_bn1_g = (const float*)d_in[16];
    const float* vort_bn1_b = (const float*)d_in[17];
    const float* vort_c2_w  = (const float*)d_in[18];
    const float* vort_bn2_g = (const float*)d_in[19];
    const float* vort_bn2_b = (const float*)d_in[20];
    const float* vort_out_w = (const float*)d_in[21];
    const float* vort_out_b = (const float*)d_in[22];
    const float* phi_weight = (const float*)d_in[23];
    const float* vort_weight= (const float*)d_in[24];
    const float* ln_g       = (const float*)d_in[25];
    const float* ln_b       = (const float*)d_in[26];
    const float* ff_w1      = (const float*)d_in[27];
    const float* ff_b1      = (const float*)d_in[28];
    const float* ff_w2      = (const float*)d_in[29];
    const float* ff_b2      = (const float*)d_in[30];

    float* ws  = (float*)d_ws;
    float* out = (float*)d_out;

    float* w_corr  = ws + CORR_OFF;
    float* w_c1p   = ws + C1P_OFF;
    float* w_c1v   = ws + C1V_OFF;
    float* w_stats = ws + STATS_OFF;
    float* w_big   = ws;                 // reused: conv2_phi / conv2_vort / phi1 / pred

    float* o_x    = out + X_OFF;         // f_nm / up_phi / phi2
    float* o_helm = out + HELM_OFF;
    float* o_vel  = out + VEL_OFF;       // f_pm,f_pb / up_vort
    float* o_vphi = out + VPHI_OFF;
    float* o_vvort= out + VVORT_OFF;

    double* d_part = (double*)o_x;       // BN partials in dead X region

    dim3 b256(256);
    dim3 gs2((S2_3 + 255)/256, NG);      // 141 x 8
    dim3 gs1((S1_3 + 255)/256, NG);      // 1124 x 8
    dim3 gs1c((S1_3 + 255)/256, NG*CG);  // 1124 x 64
    dim3 gs3((S3_3 + 255)/256, NG);      // 1024 x 8
    dim3 gmlp((S3_3 + 255)/256);         // 1024
    dim3 gstat(NBLK_STAT, 8);            // 256 x 8
    dim3 gc1(NTX*NTY*NTZ, NG);           // 225 x 8

    // ---- encoder + correlation ----
    enc_kernel<<<gs2, b256, 0, stream>>>(nxt,  mask,     enc_w, enc_b, o_x);   // f_nm
    enc_kernel<<<gs2, b256, 0, stream>>>(prev, mask,     enc_w, enc_b, o_vel); // f_pm
    corr_kernel<<<gs2, b256, 0, stream>>>(o_vel, o_x, w_corr, 0);
    enc_kernel<<<gs2, b256, 0, stream>>>(prev, boundary, enc_w, enc_b, o_vel); // f_pb
    corr_kernel<<<gs2, b256, 0, stream>>>(o_vel, o_x, w_corr, 27);

    // ---- FUSED conv1 (54->8+8, 33^3) + BN stats ----
    conv1_fused_kernel<<<gc1, b256, 0, stream>>>(w_corr, phi_c1_w, vort_c1_w,
                                                 w_c1p, w_c1v);
    bn_part_kernel  <<<gstat, b256, 0, stream>>>(w_c1p, S2_3, d_part);
    bn_finish_kernel<<<8,     b256, 0, stream>>>(d_part, S2_3, w_stats + 0);
    bn_part_kernel  <<<gstat, b256, 0, stream>>>(w_c1v, S2_3, d_part);
    bn_finish_kernel<<<8,     b256, 0, stream>>>(d_part, S2_3, w_stats + 16);

    // ---- BN+ReLU+upsample to 66^3 ----
    bn_relu_up_kernel<<<gs1c, b256, 0, stream>>>(w_c1p, w_stats + 0,  phi_bn1_g,  phi_bn1_b,  o_x);
    bn_relu_up_kernel<<<gs1c, b256, 0, stream>>>(w_c1v, w_stats + 16, vort_bn1_g, vort_bn1_b, o_vel);

    // ---- conv2 + BN stats + out-conv ----
    conv3_kernel<8,66><<<gs1, b256, 0, stream>>>(o_x, phi_c2_w, w_big);
    bn_part_kernel  <<<gstat, b256, 0, stream>>>(w_big, S1_3, d_part);
    bn_finish_kernel<<<8,     b256, 0, stream>>>(d_part, S1_3, w_stats + 32);
    outconv_kernel<1><<<gs1, b256, 0, stream>>>(w_big, w_stats + 32, phi_bn2_g, phi_bn2_b,
                                                phi_out_w, phi_out_b, phi_weight, 1.0f,
                                                o_helm, 0);
    conv3_kernel<8,66><<<gs1, b256, 0, stream>>>(o_vel, vort_c2_w, w_big);
    bn_part_kernel  <<<gstat, b256, 0, stream>>>(w_big, S1_3, d_part);
    bn_finish_kernel<<<8,     b256, 0, stream>>>(d_part, S1_3, w_stats + 48);
    outconv_kernel<3><<<gs1, b256, 0, stream>>>(w_big, w_stats + 48, vort_bn2_g, vort_bn2_b,
                                                vort_out_w, vort_out_b, vort_weight, 66.0f,
                                                o_helm, 1);

    // ---- velocities ----
    velocity_kernel<<<gs3, b256, 0, stream>>>(o_helm, o_vel, o_vphi, o_vvort);

    // ---- BFECC advection ----
    advect_kernel<false><<<gs3, b256, 0, stream>>>(tex,   nullptr, o_vel,  1.f, w_big);
    advect_kernel<false><<<gs3, b256, 0, stream>>>(w_big, nullptr, o_vel, -1.f, o_x);
    advect_kernel<true ><<<gs3, b256, 0, stream>>>(tex,   o_x,     o_vel,  1.f, w_big);

    // ---- LayerNorm + MLP + residual ----
    ln_mlp_kernel<<<gmlp, b256, 0, stream>>>(w_big, ln_g, ln_b, ff_w1, ff_b1, ff_w2, ff_b2, o_x);
}

// Round 12
// 2562.578 us; speedup vs baseline: 1.6661x; 1.0340x over previous
//
#include <hip/hip_runtime.h>
#include <math.h>

// ---------------- problem geometry ----------------
constexpr int S1 = 66, S1_2 = S1*S1, S1_3 = S1*S1*S1;   // 4356, 287496
constexpr int S2 = 33, S2_2 = S2*S2, S2_3 = S2*S2*S2;   // 1089, 35937
constexpr int S3 = 64, S3_2 = S3*S3, S3_3 = S3*S3*S3;   // 4096, 262144
constexpr int NG = 8;    // groups
constexpr int CG = 8;    // channels per group
constexpr int D  = 64;   // total channels

// ---------------- d_out layout (floats) ----------------
constexpr size_t X_OFF     = 0;                                   // x: 16,777,216
constexpr size_t HELM_OFF  = (size_t)D*S3_3;
constexpr size_t VEL_OFF   = HELM_OFF + (size_t)NG*4*S1_3;
constexpr size_t VPHI_OFF  = VEL_OFF  + (size_t)NG*3*S3_3;
constexpr size_t VVORT_OFF = VPHI_OFF + (size_t)NG*3*S3_3;

// ---------------- d_ws layout (floats) ----------------
constexpr size_t CORR_OFF  = 0;                                   // 8*54*33^3
constexpr size_t C1P_OFF   = CORR_OFF + (size_t)NG*54*S2_3;
constexpr size_t C1V_OFF   = C1P_OFF  + (size_t)NG*8*S2_3;
constexpr size_t STATS_OFF = C1V_OFF  + (size_t)NG*8*S2_3;
// ws+0 reused later for: conv2_phi, conv2_vort, phi1, pred

// BN partials (32 KB) at the start of the X region of d_out (dead at all 4
// stat points; round-5 liveness audit). NOT vel_phi (round-4 bug).
constexpr int NBLK_STAT = 256;

// =====================================================================
// encoder
// =====================================================================
__global__ void __launch_bounds__(256)
enc_kernel(const float* __restrict__ in, const float* __restrict__ msk,
           const float* __restrict__ w,  const float* __restrict__ b,
           float* __restrict__ out) {
    int pos = blockIdx.x*256 + threadIdx.x;
    int g = blockIdx.y;
    if (pos >= S2_3) return;
    int x = pos / S2_2, rem = pos % S2_2, y = rem / S2, z = rem % S2;
    int ib = 2*x*S1_2 + 2*y*S1 + 2*z;
    float mv[8];
#pragma unroll
    for (int c = 0; c < 8; ++c) {
        int dx = c>>2, dy = (c>>1)&1, dz = c&1;
        mv[c] = msk[ib + dx*S1_2 + dy*S1 + dz];
    }
    float mi[64];
#pragma unroll
    for (int ic = 0; ic < 8; ++ic) {
        const float* inc = in + (size_t)(g*CG + ic)*S1_3 + ib;
#pragma unroll
        for (int c = 0; c < 8; ++c) {
            int dx = c>>2, dy = (c>>1)&1, dz = c&1;
            mi[ic*8 + c] = inc[dx*S1_2 + dy*S1 + dz] * mv[c];
        }
    }
    for (int oc = 0; oc < 64; ++oc) {
        float acc = b[oc];
#pragma unroll
        for (int t = 0; t < 64; ++t) acc = fmaf(mi[t], w[oc*64 + t], acc);
        out[(size_t)(g*64 + oc)*S2_3 + pos] = acc;
    }
}

// =====================================================================
// correlation half
// =====================================================================
__global__ void __launch_bounds__(256)
corr_kernel(const float* __restrict__ fpv, const float* __restrict__ fnv,
            float* __restrict__ corr, int base_ch) {
    int pos = blockIdx.x*256 + threadIdx.x;
    int g = blockIdx.y;
    if (pos >= S2_3) return;
    int x = pos / S2_2, rem = pos % S2_2, y = rem / S2, z = rem % S2;
    const float* fp = fpv + (size_t)g*64*S2_3;
    const float* fn = fnv + (size_t)g*64*S2_3;
    int   nidx[9];
    float nmask[9];
#pragma unroll
    for (int di = -1; di <= 1; ++di) {
        int xx = x + di; int xc = min(max(xx,0),S2-1); bool okx = (unsigned)xx < (unsigned)S2;
#pragma unroll
        for (int dj = -1; dj <= 1; ++dj) {
            int yy = y + dj; int yc = min(max(yy,0),S2-1);
            bool ok = okx && ((unsigned)yy < (unsigned)S2);
            nidx [(di+1)*3 + dj+1] = xc*S2_2 + yc*S2 + z;
            nmask[(di+1)*3 + dj+1] = ok ? 1.f : 0.f;
        }
    }
    float acc[9] = {0,0,0,0,0,0,0,0,0};
    for (int c = 0; c < 64; ++c) {
        float pc = fp[(size_t)c*S2_3 + pos];
        const float* fnc = fn + (size_t)c*S2_3;
#pragma unroll
        for (int s = 0; s < 9; ++s) acc[s] = fmaf(pc, fnc[nidx[s]]*nmask[s], acc[s]);
    }
    const float inv64 = 1.f/64.f;
#pragma unroll
    for (int k = 0; k < 3; ++k) {
        float zf = ((k==0 && z==S2-1) || (k==2 && z==0)) ? 0.f : inv64;
#pragma unroll
        for (int s = 0; s < 9; ++s)
            corr[(size_t)(g*54 + base_ch + k*9 + s)*S2_3 + pos] = acc[s]*zf;
    }
}

// =====================================================================
// FUSED conv1: 54ch -> 8 (phi) + 8 (vort) at 33^3, LDS-tiled, pipelined.
// Round-10 post-mortem: VGPR=32 starved the allocator -> v[27] could not
// stay live -> ds_read/FMA interleave exposed LDS latency (VALUBusy 33%).
// Fix: __launch_bounds__(256,4) (VGPR ceiling 128) so v[27]+16 acc live in
// registers, + staging addresses hoisted out of the ic loop (they are
// loop-invariant; only the channel base changes).
// =====================================================================
constexpr int TLX = 4, TLY = 8, TLZ = 8;
constexpr int NTX = 9, NTY = 5, NTZ = 5;          // 36,40,40 cover 33
constexpr int HLX = TLX+2, HLY = TLY+2, HLZ = TLZ+2;  // 6,10,10
constexpr int LZP = 12;                            // padded z-stride
constexpr int TILE_N = HLX*HLY*LZP;                // 720 floats

__global__ void __launch_bounds__(256, 4)
conv1_fused_kernel(const float* __restrict__ in,
                   const float* __restrict__ wp,  // phi  (8,54,3,3,3)
                   const float* __restrict__ wv,  // vort (8,54,3,3,3)
                   float* __restrict__ outp, float* __restrict__ outv) {
    __shared__ float tile[TILE_N];
    int tid = threadIdx.x;
    int g = blockIdx.y;
    int b = blockIdx.x;
    int bx = b / (NTY*NTZ), brem = b % (NTY*NTZ), by = brem / NTZ, bz = brem % NTZ;
    int X0 = bx*TLX, Y0 = by*TLY, Z0 = bz*TLZ;
    int tx = tid >> 6, ty = (tid >> 3) & 7, tz = tid & 7;   // 4x8x8
    int gx = X0 + tx, gy = Y0 + ty, gz = Z0 + tz;
    bool valid = (gx < S2) && (gy < S2) && (gz < S2);
    const float* gbase = in + (size_t)g*54*S2_3;

    // staging addresses are loop-invariant: compute once (round-10 fix)
    int  goff[3];
    bool gok[3];
#pragma unroll
    for (int k = 0; k < 3; ++k) {
        int i = tid + k*256;
        int lx = i / (HLY*LZP), lr = i % (HLY*LZP), ly = lr / LZP, lz = lr % LZP;
        int ax = X0-1+lx, ay = Y0-1+ly, az = Z0-1+lz;
        bool ok = (i < TILE_N)
               && (unsigned)ax < (unsigned)S2
               && (unsigned)ay < (unsigned)S2
               && (unsigned)az < (unsigned)S2;
        gok[k]  = ok;
        goff[k] = ok ? (ax*S2_2 + ay*S2 + az) : 0;
    }

    float accP[8] = {0,0,0,0,0,0,0,0};
    float accV[8] = {0,0,0,0,0,0,0,0};
    float r0, r1, r2;
    {
        const float* base = gbase;                  // ic = 0
        r0 = gok[0] ? base[goff[0]] : 0.f;
        r1 = gok[1] ? base[goff[1]] : 0.f;
        r2 = gok[2] ? base[goff[2]] : 0.f;
    }

    for (int ic = 0; ic < 54; ++ic) {
        __syncthreads();                       // prev compute done; LDS free
        tile[tid]       = r0;
        tile[tid + 256] = r1;
        if (tid < TILE_N - 512) tile[tid + 512] = r2;
        float n0 = 0.f, n1 = 0.f, n2 = 0.f;
        if (ic + 1 < 54) {                     // next channel, in flight
            const float* base = gbase + (size_t)(ic + 1)*S2_3;
            n0 = gok[0] ? base[goff[0]] : 0.f;
            n1 = gok[1] ? base[goff[1]] : 0.f;
            n2 = gok[2] ? base[goff[2]] : 0.f;
        }
        __syncthreads();                       // LDS visible

        float v[27];
#pragma unroll
        for (int dx = 0; dx < 3; ++dx)
#pragma unroll
            for (int dy = 0; dy < 3; ++dy)
#pragma unroll
                for (int dz = 0; dz < 3; ++dz)
                    v[dx*9 + dy*3 + dz] =
                        tile[(tx+dx)*(HLY*LZP) + (ty+dy)*LZP + (tz+dz)];
#pragma unroll
        for (int oc = 0; oc < 8; ++oc) {
            const float* wpr = wp + (size_t)(oc*54 + ic)*27;  // uniform -> s_load
            const float* wvr = wv + (size_t)(oc*54 + ic)*27;
#pragma unroll
            for (int t = 0; t < 27; ++t) {
                accP[oc] = fmaf(v[t], wpr[t], accP[oc]);
                accV[oc] = fmaf(v[t], wvr[t], accV[oc]);
            }
        }
        r0 = n0; r1 = n1; r2 = n2;
    }

    if (valid) {
        int pos = gx*S2_2 + gy*S2 + gz;
#pragma unroll
        for (int oc = 0; oc < 8; ++oc) {
            outp[(size_t)(g*8 + oc)*S2_3 + pos] = accP[oc];
            outv[(size_t)(g*8 + oc)*S2_3 + pos] = accV[oc];
        }
    }
}

// =====================================================================
// generic 3x3x3 pad-1 conv, NIC -> 8 (still used for the 8->8 @66^3 convs)
// =====================================================================
template<int NIC, int S_>
__global__ void __launch_bounds__(256)
conv3_kernel(const float* __restrict__ in, const float* __restrict__ w,
             float* __restrict__ out) {
    constexpr int SS = S_*S_, SSS = S_*S_*S_;
    int pos = blockIdx.x*256 + threadIdx.x;
    int g = blockIdx.y;
    if (pos >= SSS) return;
    int x = pos / SS, rem = pos % SS, y = rem / S_, z = rem % S_;
    float acc[8] = {0,0,0,0,0,0,0,0};
    for (int ic = 0; ic < NIC; ++ic) {
        const float* inc = in + (size_t)(g*NIC + ic)*SSS;
        float v[27];
#pragma unroll
        for (int dx = -1; dx <= 1; ++dx) {
            int xx = x + dx; int xc = min(max(xx,0),S_-1); bool okx = (unsigned)xx < (unsigned)S_;
#pragma unroll
            for (int dy = -1; dy <= 1; ++dy) {
                int yy = y + dy; int yc = min(max(yy,0),S_-1);
                bool oky = okx && ((unsigned)yy < (unsigned)S_);
#pragma unroll
                for (int dz = -1; dz <= 1; ++dz) {
                    int zz = z + dz; int zc = min(max(zz,0),S_-1);
                    bool ok = oky && ((unsigned)zz < (unsigned)S_);
                    float t = inc[xc*SS + yc*S_ + zc];
                    v[(dx+1)*9 + (dy+1)*3 + (dz+1)] = ok ? t : 0.f;
                }
            }
        }
#pragma unroll
        for (int oc = 0; oc < 8; ++oc) {
            const float* wr = w + (size_t)(oc*NIC + ic)*27;
#pragma unroll
            for (int t = 0; t < 27; ++t) acc[oc] = fmaf(v[t], wr[t], acc[oc]);
        }
    }
#pragma unroll
    for (int oc = 0; oc < 8; ++oc)
        out[(size_t)(g*8 + oc)*SSS + pos] = acc[oc];
}

// =====================================================================
// BN stats, two-stage
// =====================================================================
__global__ void __launch_bounds__(256)
bn_part_kernel(const float* __restrict__ in, int npos, double* __restrict__ part) {
    int ch = blockIdx.y;
    int blk = blockIdx.x;
    int tid = threadIdx.x;
    double s = 0.0, ss = 0.0;
    for (int g = 0; g < NG; ++g) {
        const float* p = in + (size_t)(g*8 + ch)*npos;
        for (int i = blk*256 + tid; i < npos; i += NBLK_STAT*256) {
            double v = p[i]; s += v; ss += v*v;
        }
    }
    __shared__ double sd[256], sd2[256];
    sd[tid] = s; sd2[tid] = ss; __syncthreads();
    for (int o = 128; o > 0; o >>= 1) {
        if (tid < o) { sd[tid] += sd[tid+o]; sd2[tid] += sd2[tid+o]; }
        __syncthreads();
    }
    if (tid == 0) {
        part[((size_t)ch*NBLK_STAT + blk)*2    ] = sd[0];
        part[((size_t)ch*NBLK_STAT + blk)*2 + 1] = sd2[0];
    }
}

__global__ void __launch_bounds__(256)
bn_finish_kernel(const double* __restrict__ part, int npos, float* __restrict__ stats) {
    int ch = blockIdx.x;
    int tid = threadIdx.x;
    __shared__ double sd[256], sd2[256];
    sd[tid]  = part[((size_t)ch*NBLK_STAT + tid)*2];
    sd2[tid] = part[((size_t)ch*NBLK_STAT + tid)*2 + 1];
    __syncthreads();
    for (int o = 128; o > 0; o >>= 1) {
        if (tid < o) { sd[tid] += sd[tid+o]; sd2[tid] += sd2[tid+o]; }
        __syncthreads();
    }
    if (tid == 0) {
        double n = (double)npos * NG;
        double mean = sd[0]/n;
        double var  = sd2[0]/n - mean*mean;
        stats[ch*2]   = (float)mean;
        stats[ch*2+1] = (float)(1.0/sqrt(var + 1e-5));
    }
}

// =====================================================================
// fused BN + ReLU + x2 trilinear upsample 33^3 -> 66^3
// =====================================================================
__global__ void __launch_bounds__(256)
bn_relu_up_kernel(const float* __restrict__ in, const float* __restrict__ stats,
                  const float* __restrict__ gamma, const float* __restrict__ beta,
                  float* __restrict__ out) {
    int pos = blockIdx.x*256 + threadIdx.x;
    if (pos >= S1_3) return;
    int gc = blockIdx.y;           // g*8+ch
    int ch = gc & 7;
    int X = pos / S1_2, rem = pos % S1_2, Y = rem / S1, Z = rem % S1;
    const float scale = (float)(32.0/65.0);
    float sx = (float)X*scale, sy = (float)Y*scale, sz = (float)Z*scale;
    int x0 = (int)floorf(sx), y0 = (int)floorf(sy), z0 = (int)floorf(sz);
    float wx = sx - (float)x0, wy = sy - (float)y0, wz = sz - (float)z0;
    int x1 = min(x0+1, S2-1), y1 = min(y0+1, S2-1), z1 = min(z0+1, S2-1);
    float a = stats[ch*2+1]*gamma[ch];
    float c = beta[ch] - stats[ch*2]*a;
    const float* p = in + (size_t)gc*S2_3;
    auto val = [&](int xi, int yi, int zi) {
        float t = fmaf(p[xi*S2_2 + yi*S2 + zi], a, c);
        return t > 0.f ? t : 0.f;
    };
    float t00 = val(x0,y0,z0)*(1.f-wx) + val(x1,y0,z0)*wx;
    float t10 = val(x0,y1,z0)*(1.f-wx) + val(x1,y1,z0)*wx;
    float t01 = val(x0,y0,z1)*(1.f-wx) + val(x1,y0,z1)*wx;
    float t11 = val(x0,y1,z1)*(1.f-wx) + val(x1,y1,z1)*wx;
    float u0 = t00*(1.f-wy) + t10*wy;
    float u1 = t01*(1.f-wy) + t11*wy;
    out[(size_t)gc*S1_3 + pos] = u0*(1.f-wz) + u1*wz;
}

// =====================================================================
// fused BN + ReLU + 1x1x1 conv -> helm channels
// =====================================================================
template<int NOC>
__global__ void __launch_bounds__(256)
outconv_kernel(const float* __restrict__ in, const float* __restrict__ stats,
               const float* __restrict__ gamma, const float* __restrict__ beta,
               const float* __restrict__ ow, const float* __restrict__ ob,
               const float* __restrict__ wscale, float extra,
               float* __restrict__ helm, int oc_off) {
    int pos = blockIdx.x*256 + threadIdx.x;
    int g = blockIdx.y;
    if (pos >= S1_3) return;
    float r[8];
#pragma unroll
    for (int ic = 0; ic < 8; ++ic) {
        float a = stats[ic*2+1]*gamma[ic];
        float c = beta[ic] - stats[ic*2]*a;
        float t = fmaf(in[(size_t)(g*8 + ic)*S1_3 + pos], a, c);
        r[ic] = t > 0.f ? t : 0.f;
    }
    float sc = wscale[0]*extra;
#pragma unroll
    for (int oc = 0; oc < NOC; ++oc) {
        float acc = ob[oc];
#pragma unroll
        for (int ic = 0; ic < 8; ++ic) acc = fmaf(r[ic], ow[oc*8 + ic], acc);
        helm[(size_t)(g*4 + oc_off + oc)*S1_3 + pos] = acc*sc;
    }
}

// =====================================================================
// velocity
// =====================================================================
__global__ void __launch_bounds__(256)
velocity_kernel(const float* __restrict__ helm, float* __restrict__ vel,
                float* __restrict__ vphi, float* __restrict__ vvort) {
    int pos = blockIdx.x*256 + threadIdx.x;
    int g = blockIdx.y;
    if (pos >= S3_3) return;
    int x = pos / S3_2, rem = pos % S3_2, y = rem / S3, z = rem % S3;
    const float* H = helm + (size_t)g*4*S1_3;
    auto idx = [&](int c, int i, int j, int k) { return (size_t)c*S1_3 + i*S1_2 + j*S1 + k; };
    float pu = 0.5f*(H[idx(0,x+1,y+1,z+2)] - H[idx(0,x+1,y+1,z  )]);
    float pv = 0.5f*(H[idx(0,x+1,y+2,z+1)] - H[idx(0,x+1,y  ,z+1)]);
    float pw = 0.5f*(H[idx(0,x+2,y+1,z+1)] - H[idx(0,x  ,y+1,z+1)]);
    float vu = 0.5f*( (H[idx(2,x+2,y+1,z+1)]-H[idx(2,x+1,y+1,z+1)]) - (H[idx(1,x+1,y+2,z+1)]-H[idx(1,x+1,y+1,z+1)])
                    + (H[idx(2,x+2,y+1,z  )]-H[idx(2,x+1,y+1,z  )]) - (H[idx(1,x+1,y+2,z  )]-H[idx(1,x+1,y+1,z  )]) );
    float vv = 0.5f*( (H[idx(1,x+1,y+1,z+2)]-H[idx(1,x+1,y+1,z+1)]) - (H[idx(3,x+2,y+1,z+1)]-H[idx(3,x+1,y+1,z+1)])
                    + (H[idx(1,x+1,y  ,z+2)]-H[idx(1,x+1,y  ,z+1)]) - (H[idx(3,x+2,y  ,z+1)]-H[idx(3,x+1,y  ,z+1)]) );
    float vw = 0.5f*( (H[idx(3,x+1,y+2,z+1)]-H[idx(3,x+1,y+1,z+1)]) - (H[idx(2,x+1,y+1,z+2)]-H[idx(2,x+1,y+1,z+1)])
                    + (H[idx(3,x  ,y+2,z+1)]-H[idx(3,x  ,y+1,z+1)]) - (H[idx(2,x  ,y+1,z+2)]-H[idx(2,x  ,y+1,z+1)]) );
    size_t o0 = (size_t)(g*3+0)*S3_3 + pos;
    size_t o1 = (size_t)(g*3+1)*S3_3 + pos;
    size_t o2 = (size_t)(g*3+2)*S3_3 + pos;
    vphi[o0] = pu;      vphi[o1] = pv;      vphi[o2] = pw;
    vvort[o0] = vu;     vvort[o1] = vv;     vvort[o2] = vw;
    vel[o0] = pu + vu;  vel[o1] = pv + vv;  vel[o2] = pw + vw;
}

// =====================================================================
// trilinear advection
// =====================================================================
template<bool BFECC>
__global__ void __launch_bounds__(256)
advect_kernel(const float* __restrict__ f, const float* __restrict__ f2,
              const float* __restrict__ vel, float vsign,
              float* __restrict__ out) {
    int pos = blockIdx.x*256 + threadIdx.x;
    int g = blockIdx.y;
    if (pos >= S3_3) return;
    int x = pos / S3_2, rem = pos % S3_2, y = rem / S3, z = rem % S3;
    float px = (float)x - vsign*vel[(size_t)(g*3+2)*S3_3 + pos];
    float py = (float)y - vsign*vel[(size_t)(g*3+1)*S3_3 + pos];
    float pz = (float)z - vsign*vel[(size_t)(g*3+0)*S3_3 + pos];
    px = fminf(fmaxf(px, 0.f), 63.f);
    py = fminf(fmaxf(py, 0.f), 63.f);
    pz = fminf(fmaxf(pz, 0.f), 63.f);
    int x0 = (int)floorf(px), y0 = (int)floorf(py), z0 = (int)floorf(pz);
    int x1 = min(x0+1, S3-1), y1 = min(y0+1, S3-1), z1 = min(z0+1, S3-1);
    float fx = px - (float)x0, fy = py - (float)y0, fz = pz - (float)z0;
    int xo0 = x0*S3_2, xo1 = x1*S3_2, yo0 = y0*S3, yo1 = y1*S3;
    int i000 = xo0+yo0+z0, i100 = xo1+yo0+z0, i010 = xo0+yo1+z0, i110 = xo1+yo1+z0;
    int i001 = xo0+yo0+z1, i101 = xo1+yo0+z1, i011 = xo0+yo1+z1, i111 = xo1+yo1+z1;
    for (int c = 0; c < 8; ++c) {
        const float* fc  = f  + (size_t)(g*8 + c)*S3_3;
        const float* f2c = BFECC ? (f2 + (size_t)(g*8 + c)*S3_3) : nullptr;
        auto corner = [&](int i) {
            float t = fc[i];
            if (BFECC) { float p = f2c[i]; t = t + 0.5f*(t - p); }
            return t;
        };
        float g000 = corner(i000), g100 = corner(i100), g010 = corner(i010), g110 = corner(i110);
        float g001 = corner(i001), g101 = corner(i101), g011 = corner(i011), g111 = corner(i111);
        float r = ((g000*(1.f-fx) + g100*fx)*(1.f-fy) + (g010*(1.f-fx) + g110*fx)*fy)*(1.f-fz)
                + ((g001*(1.f-fx) + g101*fx)*(1.f-fy) + (g011*(1.f-fx) + g111*fx)*fy)*fz;
        out[(size_t)(g*8 + c)*S3_3 + pos] = r;
    }
}

// =====================================================================
// LayerNorm + MLP + residual
// =====================================================================
__global__ void __launch_bounds__(256)
ln_mlp_kernel(const float* __restrict__ pred,
              const float* __restrict__ lng, const float* __restrict__ lnb,
              const float* __restrict__ w1, const float* __restrict__ b1,
              const float* __restrict__ w2, const float* __restrict__ b2,
              float* __restrict__ xout) {
    int pos = blockIdx.x*256 + threadIdx.x;
    if (pos >= S3_3) return;
    float s = 0.f, ss = 0.f;
    for (int i = 0; i < 64; ++i) {
        float v = pred[(size_t)i*S3_3 + pos];
        s += v; ss += v*v;
    }
    float mu = s*(1.f/64.f);
    float var = ss*(1.f/64.f) - mu*mu;
    float rs = rsqrtf(var + 1e-5f);
    float y1[64];
#pragma unroll
    for (int j = 0; j < 64; ++j) y1[j] = b1[j];
    for (int i = 0; i < 64; ++i) {
        float v = pred[(size_t)i*S3_3 + pos];
        float hn = (v - mu)*rs*lng[i] + lnb[i];
        const float* wr = w1 + i*64;
#pragma unroll
        for (int j = 0; j < 64; ++j) y1[j] = fmaf(hn, wr[j], y1[j]);
    }
#pragma unroll
    for (int j = 0; j < 64; ++j) {
        float t = y1[j];
        y1[j] = 0.5f*t*(1.f + erff(t*0.70710678118654752f));
    }
    for (int c = 0; c < 64; ++c) {
        float acc = b2[c];
#pragma unroll
        for (int j = 0; j < 64; ++j) acc = fmaf(y1[j], w2[j*64 + c], acc);
        xout[(size_t)c*S3_3 + pos] = pred[(size_t)c*S3_3 + pos] + acc;
    }
}

// =====================================================================
extern "C" void kernel_launch(void* const* d_in, const int* in_sizes, int n_in,
                              void* d_out, int out_size, void* d_ws, size_t ws_size,
                              hipStream_t stream) {
    const float* prev       = (const float*)d_in[0];
    const float* nxt        = (const float*)d_in[1];
    const float* tex        = (const float*)d_in[2];
    const float* mask       = (const float*)d_in[3];
    const float* boundary   = (const float*)d_in[4];
    const float* enc_w      = (const float*)d_in[5];
    const float* enc_b      = (const float*)d_in[6];
    const float* phi_c1_w   = (const float*)d_in[7];
    const float* phi_bn1_g  = (const float*)d_in[8];
    const float* phi_bn1_b  = (const float*)d_in[9];
    const float* phi_c2_w   = (const float*)d_in[10];
    const float* phi_bn2_g  = (const float*)d_in[11];
    const float* phi_bn2_b  = (const float*)d_in[12];
    const float* phi_out_w  = (const float*)d_in[13];
    const float* phi_out_b  = (const float*)d_in[14];
    const float* vort_c1_w  = (const float*)d_in[15];
    const float* vort_bn1_g = (const float*)d_in[16];
    const float* vort_bn1_b = (const float*)d_in[17];
    const float* vort_c2_w  = (const float*)d_in[18];
    const float* vort_bn2_g = (const float*)d_in[19];
    const float* vort_bn2_b = (const float*)d_in[20];
    const float* vort_out_w = (const float*)d_in[21];
    const float* vort_out_b = (const float*)d_in[22];
    const float* phi_weight = (const float*)d_in[23];
    const float* vort_weight= (const float*)d_in[24];
    const float* ln_g       = (const float*)d_in[25];
    const float* ln_b       = (const float*)d_in[26];
    const float* ff_w1      = (const float*)d_in[27];
    const float* ff_b1      = (const float*)d_in[28];
    const float* ff_w2      = (const float*)d_in[29];
    const float* ff_b2      = (const float*)d_in[30];

    float* ws  = (float*)d_ws;
    float* out = (float*)d_out;

    float* w_corr  = ws + CORR_OFF;
    float* w_c1p   = ws + C1P_OFF;
    float* w_c1v   = ws + C1V_OFF;
    float* w_stats = ws + STATS_OFF;
    float* w_big   = ws;                 // reused: conv2_phi / conv2_vort / phi1 / pred

    float* o_x    = out + X_OFF;         // f_nm / up_phi / phi2
    float* o_helm = out + HELM_OFF;
    float* o_vel  = out + VEL_OFF;       // f_pm,f_pb / up_vort
    float* o_vphi = out + VPHI_OFF;
    float* o_vvort= out + VVORT_OFF;

    double* d_part = (double*)o_x;       // BN partials in dead X region

    dim3 b256(256);
    dim3 gs2((S2_3 + 255)/256, NG);      // 141 x 8
    dim3 gs1((S1_3 + 255)/256, NG);      // 1124 x 8
    dim3 gs1c((S1_3 + 255)/256, NG*CG);  // 1124 x 64
    dim3 gs3((S3_3 + 255)/256, NG);      // 1024 x 8
    dim3 gmlp((S3_3 + 255)/256);         // 1024
    dim3 gstat(NBLK_STAT, 8);            // 256 x 8
    dim3 gc1(NTX*NTY*NTZ, NG);           // 225 x 8

    // ---- encoder + correlation ----
    enc_kernel<<<gs2, b256, 0, stream>>>(nxt,  mask,     enc_w, enc_b, o_x);   // f_nm
    enc_kernel<<<gs2, b256, 0, stream>>>(prev, mask,     enc_w, enc_b, o_vel); // f_pm
    corr_kernel<<<gs2, b256, 0, stream>>>(o_vel, o_x, w_corr, 0);
    enc_kernel<<<gs2, b256, 0, stream>>>(prev, boundary, enc_w, enc_b, o_vel); // f_pb
    corr_kernel<<<gs2, b256, 0, stream>>>(o_vel, o_x, w_corr, 27);

    // ---- FUSED conv1 (54->8+8, 33^3) + BN stats ----
    conv1_fused_kernel<<<gc1, b256, 0, stream>>>(w_corr, phi_c1_w, vort_c1_w,
                                                 w_c1p, w_c1v);
    bn_part_kernel  <<<gstat, b256, 0, stream>>>(w_c1p, S2_3, d_part);
    bn_finish_kernel<<<8,     b256, 0, stream>>>(d_part, S2_3, w_stats + 0);
    bn_part_kernel  <<<gstat, b256, 0, stream>>>(w_c1v, S2_3, d_part);
    bn_finish_kernel<<<8,     b256, 0, stream>>>(d_part, S2_3, w_stats + 16);

    // ---- BN+ReLU+upsample to 66^3 ----
    bn_relu_up_kernel<<<gs1c, b256, 0, stream>>>(w_c1p, w_stats + 0,  phi_bn1_g,  phi_bn1_b,  o_x);
    bn_relu_up_kernel<<<gs1c, b256, 0, stream>>>(w_c1v, w_stats + 16, vort_bn1_g, vort_bn1_b, o_vel);

    // ---- conv2 + BN stats + out-conv ----
    conv3_kernel<8,66><<<gs1, b256, 0, stream>>>(o_x, phi_c2_w, w_big);
    bn_part_kernel  <<<gstat, b256, 0, stream>>>(w_big, S1_3, d_part);
    bn_finish_kernel<<<8,     b256, 0, stream>>>(d_part, S1_3, w_stats + 32);
    outconv_kernel<1><<<gs1, b256, 0, stream>>>(w_big, w_stats + 32, phi_bn2_g, phi_bn2_b,
                                                phi_out_w, phi_out_b, phi_weight, 1.0f,
                                                o_helm, 0);
    conv3_kernel<8,66><<<gs1, b256, 0, stream>>>(o_vel, vort_c2_w, w_big);
    bn_part_kernel  <<<gstat, b256, 0, stream>>>(w_big, S1_3, d_part);
    bn_finish_kernel<<<8,     b256, 0, stream>>>(d_part, S1_3, w_stats + 48);
    outconv_kernel<3><<<gs1, b256, 0, stream>>>(w_big, w_stats + 48, vort_bn2_g, vort_bn2_b,
                                                vort_out_w, vort_out_b, vort_weight, 66.0f,
                                                o_helm, 1);

    // ---- velocities ----
    velocity_kernel<<<gs3, b256, 0, stream>>>(o_helm, o_vel, o_vphi, o_vvort);

    // ---- BFECC advection ----
    advect_kernel<false><<<gs3, b256, 0, stream>>>(tex,   nullptr, o_vel,  1.f, w_big);
    advect_kernel<false><<<gs3, b256, 0, stream>>>(w_big, nullptr, o_vel, -1.f, o_x);
    advect_kernel<true ><<<gs3, b256, 0, stream>>>(tex,   o_x,     o_vel,  1.f, w_big);

    // ---- LayerNorm + MLP + residual ----
    ln_mlp_kernel<<<gmlp, b256, 0, stream>>>(w_big, ln_g, ln_b, ff_w1, ff_b1, ff_w2, ff_b2, o_x);
}